// Round 2
// baseline (574.864 us; speedup 1.0000x reference)
//
#include <hip/hip_runtime.h>
#include <stdint.h>

#define GRID 200
#define CIN 6
#define COUT 32
#define NOFF 27
#define BN_EPS 1e-5f

// ---------------- table build ----------------

__global__ void build_dense(const int* __restrict__ coords, int N, int* __restrict__ grid) {
    int i = blockIdx.x * blockDim.x + threadIdx.x;
    if (i >= N) return;
    int x = coords[3 * i], y = coords[3 * i + 1], z = coords[3 * i + 2];
    grid[(x * GRID + y) * GRID + z] = i;
}

__global__ void build_hash(const int* __restrict__ coords, int N,
                           unsigned long long* __restrict__ table,
                           uint32_t bits, uint32_t mask) {
    int i = blockIdx.x * blockDim.x + threadIdx.x;
    if (i >= N) return;
    int x = coords[3 * i], y = coords[3 * i + 1], z = coords[3 * i + 2];
    uint32_t key = (uint32_t)((x * GRID + y) * GRID + z);
    unsigned long long packed = ((unsigned long long)key << 32) | (uint32_t)i;
    uint32_t h = (key * 2654435761u) >> (32u - bits);
    for (uint32_t p = 0; p <= mask; p++) {                 // bounded probing
        unsigned long long prev = atomicCAS(&table[h], ~0ull, packed);
        if (prev == ~0ull) return;
        h = (h + 1) & mask;
    }
}

__device__ __forceinline__ int lookup_hash(const unsigned long long* __restrict__ t,
                                           uint32_t key, uint32_t bits, uint32_t mask) {
    uint32_t h = (key * 2654435761u) >> (32u - bits);
    for (uint32_t p = 0; p <= mask; p++) {                 // bounded probing
        unsigned long long e = t[h];
        if (e == ~0ull) return -1;
        if ((uint32_t)(e >> 32) == key) return (int)(uint32_t)e;
        h = (h + 1) & mask;
    }
    return -1;
}

// ---------------- conv ----------------

template <bool DENSE>
__global__ __launch_bounds__(256)
void conv_kernel(const float* __restrict__ feat,
                 const int* __restrict__ coords,
                 const float* __restrict__ W,
                 const void* __restrict__ table,
                 uint32_t bits, uint32_t mask, int N,
                 float* __restrict__ out) {
    __shared__ __align__(16) float wlds[NOFF * CIN * COUT];   // 5184 f32 = 20.25 KB
    for (int t = threadIdx.x; t < NOFF * CIN * COUT; t += blockDim.x)
        wlds[t] = W[t];
    __syncthreads();

    int i = blockIdx.x * blockDim.x + threadIdx.x;
    if (i >= N) return;

    int x = coords[3 * i], y = coords[3 * i + 1], z = coords[3 * i + 2];

    float acc[COUT];
#pragma unroll
    for (int c = 0; c < COUT; c++) acc[c] = 0.f;

#pragma unroll 1
    for (int k = 0; k < NOFF; k++) {
        int dx = k / 9 - 1, dy = (k / 3) % 3 - 1, dz = k % 3 - 1;
        int nx = x + dx, ny = y + dy, nz = z + dz;
        int idx = -1;
        if ((unsigned)nx < GRID && (unsigned)ny < GRID && (unsigned)nz < GRID) {
            uint32_t key = (uint32_t)((nx * GRID + ny) * GRID + nz);
            if (DENSE) idx = ((const int*)table)[key];
            else       idx = lookup_hash((const unsigned long long*)table, key, bits, mask);
        }
        if (idx >= 0) {
            const float* fr = feat + (size_t)idx * CIN;     // 24B-aligned row
            float2 a = *(const float2*)(fr);
            float2 b = *(const float2*)(fr + 2);
            float2 c2 = *(const float2*)(fr + 4);
            float f[CIN] = {a.x, a.y, b.x, b.y, c2.x, c2.y};
            const float* wk = &wlds[k * CIN * COUT];
#pragma unroll
            for (int ci = 0; ci < CIN; ci++) {
                const float4* w4 = (const float4*)(wk + ci * COUT);
                float fv = f[ci];
#pragma unroll
                for (int q = 0; q < COUT / 4; q++) {
                    float4 wv = w4[q];
                    acc[4 * q + 0] += fv * wv.x;
                    acc[4 * q + 1] += fv * wv.y;
                    acc[4 * q + 2] += fv * wv.z;
                    acc[4 * q + 3] += fv * wv.w;
                }
            }
        }
    }

    float4* op = (float4*)(out + (size_t)i * COUT);         // 128B-aligned row
#pragma unroll
    for (int q = 0; q < COUT / 4; q++) {
        float4 v;
        v.x = acc[4 * q + 0];
        v.y = acc[4 * q + 1];
        v.z = acc[4 * q + 2];
        v.w = acc[4 * q + 3];
        op[q] = v;
    }
}

// ---------------- BN stats ----------------

__global__ __launch_bounds__(256)
void stats_kernel(const float* __restrict__ out, long total_vec,
                  float* __restrict__ stats) {
    __shared__ float lsum[COUT], lsq[COUT];
    for (int t = threadIdx.x; t < COUT; t += blockDim.x) { lsum[t] = 0.f; lsq[t] = 0.f; }
    __syncthreads();

    long stride = (long)gridDim.x * blockDim.x;          // 262144, multiple of 8
    long v0 = (long)blockIdx.x * blockDim.x + threadIdx.x;
    int cbase = (int)(v0 & 7) * 4;                       // constant per thread
    float s[4] = {0, 0, 0, 0}, q[4] = {0, 0, 0, 0};
    const float4* p = (const float4*)out;
    for (long v = v0; v < total_vec; v += stride) {
        float4 u = p[v];
        s[0] += u.x; q[0] += u.x * u.x;
        s[1] += u.y; q[1] += u.y * u.y;
        s[2] += u.z; q[2] += u.z * u.z;
        s[3] += u.w; q[3] += u.w * u.w;
    }
#pragma unroll
    for (int j = 0; j < 4; j++) {
        atomicAdd(&lsum[cbase + j], s[j]);
        atomicAdd(&lsq[cbase + j], q[j]);
    }
    __syncthreads();
    for (int t = threadIdx.x; t < COUT; t += blockDim.x) {
        atomicAdd(&stats[t], lsum[t]);
        atomicAdd(&stats[COUT + t], lsq[t]);
    }
}

__global__ void finalize_kernel(const float* __restrict__ stats,
                                const float* __restrict__ gamma,
                                const float* __restrict__ beta,
                                float invN, float* __restrict__ scaleshift) {
    int c = threadIdx.x;
    if (c < COUT) {
        float mean = stats[c] * invN;
        float var = stats[COUT + c] * invN - mean * mean;
        float sc = gamma[c] * rsqrtf(var + BN_EPS);
        scaleshift[c] = sc;
        scaleshift[COUT + c] = beta[c] - mean * sc;
    }
}

__global__ __launch_bounds__(256)
void norm_kernel(float* __restrict__ out, long total_vec,
                 const float* __restrict__ scaleshift) {
    __shared__ float sc[COUT], sh[COUT];
    for (int t = threadIdx.x; t < COUT; t += blockDim.x) {
        sc[t] = scaleshift[t];
        sh[t] = scaleshift[COUT + t];
    }
    __syncthreads();
    long stride = (long)gridDim.x * blockDim.x;          // 524288, multiple of 8
    float4* p = (float4*)out;
    for (long v = (long)blockIdx.x * blockDim.x + threadIdx.x; v < total_vec; v += stride) {
        int cbase = (int)(v & 7) * 4;
        float4 u = p[v];
        u.x = fmaxf(u.x * sc[cbase + 0] + sh[cbase + 0], 0.f);
        u.y = fmaxf(u.y * sc[cbase + 1] + sh[cbase + 1], 0.f);
        u.z = fmaxf(u.z * sc[cbase + 2] + sh[cbase + 2], 0.f);
        u.w = fmaxf(u.w * sc[cbase + 3] + sh[cbase + 3], 0.f);
        p[v] = u;
    }
}

// ---------------- launch ----------------

extern "C" void kernel_launch(void* const* d_in, const int* in_sizes, int n_in,
                              void* d_out, int out_size, void* d_ws, size_t ws_size,
                              hipStream_t stream) {
    const float* feat   = (const float*)d_in[0];
    const int*   coords = (const int*)d_in[1];
    const float* W      = (const float*)d_in[2];
    const float* gamma  = (const float*)d_in[3];
    const float* beta   = (const float*)d_in[4];
    float* out = (float*)d_out;

    int N = in_sizes[0] / CIN;
    const int threads = 256;
    int blocksN = (N + threads - 1) / threads;

    size_t dense_bytes = (size_t)GRID * GRID * GRID * sizeof(int);   // 32 MB
    bool dense = (ws_size >= dense_bytes + 512);

    size_t table_bytes;
    uint32_t bits = 22, mask = 0;
    if (dense) {
        table_bytes = dense_bytes;
    } else {
        while (bits > 20 && ((size_t)8 << bits) + 512 > ws_size) bits--;
        table_bytes = (size_t)8 << bits;
        mask = (1u << bits) - 1u;
    }

    // stats scratch REUSES the table region (table is dead after conv);
    // all ops are stream-ordered so this is safe and graph-capturable.
    float* stats = (float*)d_ws;
    float* scaleshift = stats + 2 * COUT;

    hipMemsetAsync(d_ws, 0xFF, table_bytes, stream);

    if (dense) {
        build_dense<<<blocksN, threads, 0, stream>>>(coords, N, (int*)d_ws);
        conv_kernel<true><<<blocksN, threads, 0, stream>>>(feat, coords, W, d_ws, 0, 0, N, out);
    } else {
        build_hash<<<blocksN, threads, 0, stream>>>(coords, N, (unsigned long long*)d_ws, bits, mask);
        conv_kernel<false><<<blocksN, threads, 0, stream>>>(feat, coords, W, d_ws, bits, mask, N, out);
    }

    hipMemsetAsync(stats, 0, 2 * COUT * sizeof(float), stream);
    long total_vec = (long)N * COUT / 4;   // float4 granules
    stats_kernel<<<1024, threads, 0, stream>>>(out, total_vec, stats);
    finalize_kernel<<<1, 64, 0, stream>>>(stats, gamma, beta, 1.0f / (float)N, scaleshift);
    norm_kernel<<<2048, threads, 0, stream>>>(out, total_vec, scaleshift);
}

// Round 3
// 380.762 us; speedup vs baseline: 1.5098x; 1.5098x over previous
//
#include <hip/hip_runtime.h>
#include <stdint.h>

#define GRIDX 200
#define NCELL (GRIDX * GRIDX * GRIDX)          // 8,000,000
#define CIN 6
#define COUT 32
#define NOFF 27
#define BN_EPS 1e-5f
#define CPB 4096                                // cells per compaction block
#define NBLK_C ((NCELL + CPB - 1) / CPB)        // 1954
#define PER 8                                   // scan items/thread (256*8 >= NBLK_C)

// ---------------- helpers ----------------

__device__ __forceinline__ int xcd_swizzle(int b, int nwg) {
    int q = nwg >> 3, r = nwg & 7;
    int xcd = b & 7, idx = b >> 3;
    int base = (xcd < r) ? xcd * (q + 1) : r * (q + 1) + (xcd - r) * q;
    return base + idx;
}

// ---------------- table build ----------------

__global__ void build_dense(const int* __restrict__ coords, int N, int* __restrict__ grid) {
    int i = blockIdx.x * blockDim.x + threadIdx.x;
    if (i >= N) return;
    int x = coords[3 * i], y = coords[3 * i + 1], z = coords[3 * i + 2];
    grid[(x * GRIDX + y) * GRIDX + z] = i;
}

__global__ void build_hash(const int* __restrict__ coords, int N,
                           unsigned long long* __restrict__ table,
                           uint32_t bits, uint32_t mask) {
    int i = blockIdx.x * blockDim.x + threadIdx.x;
    if (i >= N) return;
    int x = coords[3 * i], y = coords[3 * i + 1], z = coords[3 * i + 2];
    uint32_t key = (uint32_t)((x * GRIDX + y) * GRIDX + z);
    unsigned long long packed = ((unsigned long long)key << 32) | (uint32_t)i;
    uint32_t h = (key * 2654435761u) >> (32u - bits);
    for (uint32_t p = 0; p <= mask; p++) {
        unsigned long long prev = atomicCAS(&table[h], ~0ull, packed);
        if (prev == ~0ull) return;
        h = (h + 1) & mask;
    }
}

__device__ __forceinline__ int lookup_hash(const unsigned long long* __restrict__ t,
                                           uint32_t key, uint32_t bits, uint32_t mask) {
    uint32_t h = (key * 2654435761u) >> (32u - bits);
    for (uint32_t p = 0; p <= mask; p++) {
        unsigned long long e = t[h];
        if (e == ~0ull) return -1;
        if ((uint32_t)(e >> 32) == key) return (int)(uint32_t)e;
        h = (h + 1) & mask;
    }
    return -1;
}

// ---------------- compaction (sorted path) ----------------

__global__ __launch_bounds__(256)
void count_kernel(const int* __restrict__ grid, int* __restrict__ blockcounts) {
    __shared__ int tot[256];
    int b = blockIdx.x, t = threadIdx.x;
    int cell0 = b * CPB + t * 16;
    int cnt = 0;
#pragma unroll
    for (int j = 0; j < 16; j++) {
        int c = cell0 + j;
        if (c < NCELL && grid[c] >= 0) cnt++;
    }
    tot[t] = cnt;
    __syncthreads();
    if (t < 128) tot[t] += tot[t + 128];
    __syncthreads();
    if (t < 64) {
        int v = tot[t] + tot[t + 64];
#pragma unroll
        for (int d = 32; d > 0; d >>= 1) v += __shfl_down(v, d);
        if (t == 0) blockcounts[b] = v;
    }
}

__global__ __launch_bounds__(256)
void scan_kernel(const int* __restrict__ cnt, int* __restrict__ base) {
    __shared__ int tot[256];
    int t = threadIdx.x;
    int local[PER];
    int s = 0;
#pragma unroll
    for (int j = 0; j < PER; j++) {
        int idx = t * PER + j;
        int v = (idx < NBLK_C) ? cnt[idx] : 0;
        local[j] = s;
        s += v;
    }
    tot[t] = s;
    __syncthreads();
    for (int d = 1; d < 256; d <<= 1) {
        int v = (t >= d) ? tot[t - d] : 0;
        __syncthreads();
        tot[t] += v;
        __syncthreads();
    }
    int tbase = (t == 0) ? 0 : tot[t - 1];
#pragma unroll
    for (int j = 0; j < PER; j++) {
        int idx = t * PER + j;
        if (idx < NBLK_C) base[idx] = tbase + local[j];
    }
}

__global__ __launch_bounds__(256)
void fill_kernel(int* __restrict__ grid, const float* __restrict__ feat,
                 const int* __restrict__ blockbase,
                 int* __restrict__ sorted_orig, int* __restrict__ skeys,
                 float* __restrict__ feat_s) {
    __shared__ int tot[256];
    int b = blockIdx.x, t = threadIdx.x;
    int cell0 = b * CPB + t * 16;
    int myorig[16];
    int cnt = 0;
#pragma unroll
    for (int j = 0; j < 16; j++) {
        int c = cell0 + j;
        int v = (c < NCELL) ? grid[c] : -1;
        myorig[j] = v;
        cnt += (v >= 0) ? 1 : 0;
    }
    tot[t] = cnt;
    __syncthreads();
    for (int d = 1; d < 256; d <<= 1) {
        int v = (t >= d) ? tot[t - d] : 0;
        __syncthreads();
        tot[t] += v;
        __syncthreads();
    }
    int jb = blockbase[b] + ((t == 0) ? 0 : tot[t - 1]);
#pragma unroll
    for (int j = 0; j < 16; j++) {
        int v = myorig[j];
        if (v >= 0) {
            int cell = cell0 + j;
            grid[cell] = jb;                       // dense table now holds RANK
            sorted_orig[jb] = v;
            skeys[jb] = cell;
            const float* fr = feat + (size_t)v * CIN;
            float* fd = feat_s + (size_t)jb * CIN;
            float2 a = *(const float2*)fr;
            float2 bb = *(const float2*)(fr + 2);
            float2 cc = *(const float2*)(fr + 4);
            *(float2*)fd = a;
            *(float2*)(fd + 2) = bb;
            *(float2*)(fd + 4) = cc;
            jb++;
        }
    }
}

// ---------------- conv (sorted order) ----------------

__global__ __launch_bounds__(256)
void conv_sorted(const float* __restrict__ feat_s,
                 const int* __restrict__ skeys,
                 const int* __restrict__ sorted_orig,
                 const float* __restrict__ W,
                 const int* __restrict__ grid, int N,
                 float* __restrict__ out) {
    __shared__ __align__(16) float wlds[NOFF * CIN * COUT];
    for (int t = threadIdx.x; t < NOFF * CIN * COUT; t += blockDim.x)
        wlds[t] = W[t];
    __syncthreads();

    int nwg = gridDim.x;
    int sb = xcd_swizzle(blockIdx.x, nwg);
    int i = sb * blockDim.x + threadIdx.x;
    if (i >= N) return;

    uint32_t key = (uint32_t)skeys[i];
    uint32_t x = key / (GRIDX * GRIDX);
    uint32_t rem = key % (GRIDX * GRIDX);
    uint32_t y = rem / GRIDX;
    uint32_t z = rem % GRIDX;

    float acc[COUT];
#pragma unroll
    for (int c = 0; c < COUT; c++) acc[c] = 0.f;

#pragma unroll 1
    for (int k = 0; k < NOFF; k++) {
        int dx = k / 9 - 1, dy = (k / 3) % 3 - 1, dz = k % 3 - 1;
        int nx = (int)x + dx, ny = (int)y + dy, nz = (int)z + dz;
        int pos = -1;
        if ((unsigned)nx < GRIDX && (unsigned)ny < GRIDX && (unsigned)nz < GRIDX) {
            int nkey = (int)key + dx * (GRIDX * GRIDX) + dy * GRIDX + dz;
            pos = grid[nkey];
        }
        if (pos >= 0) {
            const float* fr = feat_s + (size_t)pos * CIN;
            float2 a = *(const float2*)(fr);
            float2 b = *(const float2*)(fr + 2);
            float2 c2 = *(const float2*)(fr + 4);
            float f[CIN] = {a.x, a.y, b.x, b.y, c2.x, c2.y};
            const float* wk = &wlds[k * CIN * COUT];
#pragma unroll
            for (int ci = 0; ci < CIN; ci++) {
                const float4* w4 = (const float4*)(wk + ci * COUT);
                float fv = f[ci];
#pragma unroll
                for (int q = 0; q < COUT / 4; q++) {
                    float4 wv = w4[q];
                    acc[4 * q + 0] += fv * wv.x;
                    acc[4 * q + 1] += fv * wv.y;
                    acc[4 * q + 2] += fv * wv.z;
                    acc[4 * q + 3] += fv * wv.w;
                }
            }
        }
    }

    float4* op = (float4*)(out + (size_t)sorted_orig[i] * COUT);
#pragma unroll
    for (int q = 0; q < COUT / 4; q++) {
        float4 v;
        v.x = acc[4 * q + 0];
        v.y = acc[4 * q + 1];
        v.z = acc[4 * q + 2];
        v.w = acc[4 * q + 3];
        op[q] = v;
    }
}

// ---------------- conv (unsorted fallback, R2) ----------------

template <bool DENSE>
__global__ __launch_bounds__(256)
void conv_kernel(const float* __restrict__ feat,
                 const int* __restrict__ coords,
                 const float* __restrict__ W,
                 const void* __restrict__ table,
                 uint32_t bits, uint32_t mask, int N,
                 float* __restrict__ out) {
    __shared__ __align__(16) float wlds[NOFF * CIN * COUT];
    for (int t = threadIdx.x; t < NOFF * CIN * COUT; t += blockDim.x)
        wlds[t] = W[t];
    __syncthreads();

    int i = blockIdx.x * blockDim.x + threadIdx.x;
    if (i >= N) return;
    int x = coords[3 * i], y = coords[3 * i + 1], z = coords[3 * i + 2];

    float acc[COUT];
#pragma unroll
    for (int c = 0; c < COUT; c++) acc[c] = 0.f;

#pragma unroll 1
    for (int k = 0; k < NOFF; k++) {
        int dx = k / 9 - 1, dy = (k / 3) % 3 - 1, dz = k % 3 - 1;
        int nx = x + dx, ny = y + dy, nz = z + dz;
        int idx = -1;
        if ((unsigned)nx < GRIDX && (unsigned)ny < GRIDX && (unsigned)nz < GRIDX) {
            uint32_t key = (uint32_t)((nx * GRIDX + ny) * GRIDX + nz);
            if (DENSE) idx = ((const int*)table)[key];
            else       idx = lookup_hash((const unsigned long long*)table, key, bits, mask);
        }
        if (idx >= 0) {
            const float* fr = feat + (size_t)idx * CIN;
            float2 a = *(const float2*)(fr);
            float2 b = *(const float2*)(fr + 2);
            float2 c2 = *(const float2*)(fr + 4);
            float f[CIN] = {a.x, a.y, b.x, b.y, c2.x, c2.y};
            const float* wk = &wlds[k * CIN * COUT];
#pragma unroll
            for (int ci = 0; ci < CIN; ci++) {
                const float4* w4 = (const float4*)(wk + ci * COUT);
                float fv = f[ci];
#pragma unroll
                for (int q = 0; q < COUT / 4; q++) {
                    float4 wv = w4[q];
                    acc[4 * q + 0] += fv * wv.x;
                    acc[4 * q + 1] += fv * wv.y;
                    acc[4 * q + 2] += fv * wv.z;
                    acc[4 * q + 3] += fv * wv.w;
                }
            }
        }
    }

    float4* op = (float4*)(out + (size_t)i * COUT);
#pragma unroll
    for (int q = 0; q < COUT / 4; q++) {
        float4 v;
        v.x = acc[4 * q + 0];
        v.y = acc[4 * q + 1];
        v.z = acc[4 * q + 2];
        v.w = acc[4 * q + 3];
        op[q] = v;
    }
}

// ---------------- BN stats / norm ----------------

__global__ __launch_bounds__(256)
void stats_kernel(const float* __restrict__ out, long total_vec,
                  float* __restrict__ stats) {
    __shared__ float lsum[COUT], lsq[COUT];
    for (int t = threadIdx.x; t < COUT; t += blockDim.x) { lsum[t] = 0.f; lsq[t] = 0.f; }
    __syncthreads();

    long stride = (long)gridDim.x * blockDim.x;
    long v0 = (long)blockIdx.x * blockDim.x + threadIdx.x;
    int cbase = (int)(v0 & 7) * 4;
    float s[4] = {0, 0, 0, 0}, q[4] = {0, 0, 0, 0};
    const float4* p = (const float4*)out;
    for (long v = v0; v < total_vec; v += stride) {
        float4 u = p[v];
        s[0] += u.x; q[0] += u.x * u.x;
        s[1] += u.y; q[1] += u.y * u.y;
        s[2] += u.z; q[2] += u.z * u.z;
        s[3] += u.w; q[3] += u.w * u.w;
    }
#pragma unroll
    for (int j = 0; j < 4; j++) {
        atomicAdd(&lsum[cbase + j], s[j]);
        atomicAdd(&lsq[cbase + j], q[j]);
    }
    __syncthreads();
    for (int t = threadIdx.x; t < COUT; t += blockDim.x) {
        atomicAdd(&stats[t], lsum[t]);
        atomicAdd(&stats[COUT + t], lsq[t]);
    }
}

__global__ void finalize_kernel(const float* __restrict__ stats,
                                const float* __restrict__ gamma,
                                const float* __restrict__ beta,
                                float invN, float* __restrict__ scaleshift) {
    int c = threadIdx.x;
    if (c < COUT) {
        float mean = stats[c] * invN;
        float var = stats[COUT + c] * invN - mean * mean;
        float sc = gamma[c] * rsqrtf(var + BN_EPS);
        scaleshift[c] = sc;
        scaleshift[COUT + c] = beta[c] - mean * sc;
    }
}

__global__ __launch_bounds__(256)
void norm_kernel(float* __restrict__ out, long total_vec,
                 const float* __restrict__ scaleshift) {
    __shared__ float sc[COUT], sh[COUT];
    for (int t = threadIdx.x; t < COUT; t += blockDim.x) {
        sc[t] = scaleshift[t];
        sh[t] = scaleshift[COUT + t];
    }
    __syncthreads();
    long stride = (long)gridDim.x * blockDim.x;
    float4* p = (float4*)out;
    for (long v = (long)blockIdx.x * blockDim.x + threadIdx.x; v < total_vec; v += stride) {
        int cbase = (int)(v & 7) * 4;
        float4 u = p[v];
        u.x = fmaxf(u.x * sc[cbase + 0] + sh[cbase + 0], 0.f);
        u.y = fmaxf(u.y * sc[cbase + 1] + sh[cbase + 1], 0.f);
        u.z = fmaxf(u.z * sc[cbase + 2] + sh[cbase + 2], 0.f);
        u.w = fmaxf(u.w * sc[cbase + 3] + sh[cbase + 3], 0.f);
        p[v] = u;
    }
}

// ---------------- launch ----------------

extern "C" void kernel_launch(void* const* d_in, const int* in_sizes, int n_in,
                              void* d_out, int out_size, void* d_ws, size_t ws_size,
                              hipStream_t stream) {
    const float* feat   = (const float*)d_in[0];
    const int*   coords = (const int*)d_in[1];
    const float* W      = (const float*)d_in[2];
    const float* gamma  = (const float*)d_in[3];
    const float* beta   = (const float*)d_in[4];
    float* out = (float*)d_out;

    int N = in_sizes[0] / CIN;
    const int threads = 256;
    int blocksN = (N + threads - 1) / threads;

    size_t a256 = 255;
    size_t table_b   = (size_t)NCELL * 4;                     // 32 MB
    size_t off_sorig = (table_b + a256) & ~a256;
    size_t off_skeys = (off_sorig + (size_t)N * 4 + a256) & ~a256;
    size_t off_feats = (off_skeys + (size_t)N * 4 + a256) & ~a256;
    size_t off_bcnt  = (off_feats + (size_t)N * CIN * 4 + a256) & ~a256;
    size_t off_bbase = (off_bcnt + (size_t)NBLK_C * 4 + a256) & ~a256;
    size_t off_stats = (off_bbase + (size_t)NBLK_C * 4 + a256) & ~a256;
    size_t need_sorted = off_stats + 4 * COUT * sizeof(float) + 256;

    long total_vec = (long)N * COUT / 4;

    if (ws_size >= need_sorted) {
        int*   grid  = (int*)d_ws;
        int*   sorig = (int*)((char*)d_ws + off_sorig);
        int*   skeys = (int*)((char*)d_ws + off_skeys);
        float* feats = (float*)((char*)d_ws + off_feats);
        int*   bcnt  = (int*)((char*)d_ws + off_bcnt);
        int*   bbase = (int*)((char*)d_ws + off_bbase);
        float* stats = (float*)((char*)d_ws + off_stats);
        float* scsh  = stats + 2 * COUT;

        hipMemsetAsync(d_ws, 0xFF, table_b, stream);
        hipMemsetAsync(stats, 0, 2 * COUT * sizeof(float), stream);
        build_dense<<<blocksN, threads, 0, stream>>>(coords, N, grid);
        count_kernel<<<NBLK_C, threads, 0, stream>>>(grid, bcnt);
        scan_kernel<<<1, threads, 0, stream>>>(bcnt, bbase);
        fill_kernel<<<NBLK_C, threads, 0, stream>>>(grid, feat, bbase, sorig, skeys, feats);
        conv_sorted<<<blocksN, threads, 0, stream>>>(feats, skeys, sorig, W, grid, N, out);
        stats_kernel<<<1024, threads, 0, stream>>>(out, total_vec, stats);
        finalize_kernel<<<1, 64, 0, stream>>>(stats, gamma, beta, 1.0f / (float)N, scsh);
        norm_kernel<<<2048, threads, 0, stream>>>(out, total_vec, scsh);
        return;
    }

    // ---------- fallback (R2 behavior) ----------
    size_t dense_bytes = table_b;
    bool dense = (ws_size >= dense_bytes + 512);
    size_t table_bytes;
    uint32_t bits = 22, mask = 0;
    if (dense) {
        table_bytes = dense_bytes;
    } else {
        while (bits > 20 && ((size_t)8 << bits) + 512 > ws_size) bits--;
        table_bytes = (size_t)8 << bits;
        mask = (1u << bits) - 1u;
    }
    float* stats = (float*)d_ws;
    float* scsh  = stats + 2 * COUT;

    hipMemsetAsync(d_ws, 0xFF, table_bytes, stream);
    if (dense) {
        build_dense<<<blocksN, threads, 0, stream>>>(coords, N, (int*)d_ws);
        conv_kernel<true><<<blocksN, threads, 0, stream>>>(feat, coords, W, d_ws, 0, 0, N, out);
    } else {
        build_hash<<<blocksN, threads, 0, stream>>>(coords, N, (unsigned long long*)d_ws, bits, mask);
        conv_kernel<false><<<blocksN, threads, 0, stream>>>(feat, coords, W, d_ws, bits, mask, N, out);
    }
    hipMemsetAsync(stats, 0, 2 * COUT * sizeof(float), stream);
    stats_kernel<<<1024, threads, 0, stream>>>(out, total_vec, stats);
    finalize_kernel<<<1, 64, 0, stream>>>(stats, gamma, beta, 1.0f / (float)N, scsh);
    norm_kernel<<<2048, threads, 0, stream>>>(out, total_vec, scsh);
}

// Round 4
// 298.191 us; speedup vs baseline: 1.9278x; 1.2769x over previous
//
#include <hip/hip_runtime.h>
#include <stdint.h>

#define GRIDX 200
#define NCELL (GRIDX * GRIDX * GRIDX)          // 8,000,000
#define CIN 6
#define COUT 32
#define NOFF 27
#define BN_EPS 1e-5f
#define CPB 4096                                // cells per compaction block
#define NBLK_C ((NCELL + CPB - 1) / CPB)        // 1954
#define PER 8                                   // scan items/thread

typedef __attribute__((ext_vector_type(8))) short short8;
typedef __attribute__((ext_vector_type(4))) float f32x4;

// ---------------- helpers ----------------

__device__ __forceinline__ int xcd_swizzle(int b, int nwg) {
    int q = nwg >> 3, r = nwg & 7;
    int xcd = b & 7, idx = b >> 3;
    int base = (xcd < r) ? xcd * (q + 1) : r * (q + 1) + (xcd - r) * q;
    return base + idx;
}

__device__ __forceinline__ unsigned short f2bf(float f) {
    uint32_t u = __float_as_uint(f);
    return (unsigned short)((u + 0x7FFFu + ((u >> 16) & 1u)) >> 16);   // RNE
}

// ---------------- table build ----------------

__global__ void build_dense(const int* __restrict__ coords, int N, int* __restrict__ grid) {
    int i = blockIdx.x * blockDim.x + threadIdx.x;
    if (i >= N) return;
    int x = coords[3 * i], y = coords[3 * i + 1], z = coords[3 * i + 2];
    grid[(x * GRIDX + y) * GRIDX + z] = i;
}

__global__ void build_hash(const int* __restrict__ coords, int N,
                           unsigned long long* __restrict__ table,
                           uint32_t bits, uint32_t mask) {
    int i = blockIdx.x * blockDim.x + threadIdx.x;
    if (i >= N) return;
    int x = coords[3 * i], y = coords[3 * i + 1], z = coords[3 * i + 2];
    uint32_t key = (uint32_t)((x * GRIDX + y) * GRIDX + z);
    unsigned long long packed = ((unsigned long long)key << 32) | (uint32_t)i;
    uint32_t h = (key * 2654435761u) >> (32u - bits);
    for (uint32_t p = 0; p <= mask; p++) {
        unsigned long long prev = atomicCAS(&table[h], ~0ull, packed);
        if (prev == ~0ull) return;
        h = (h + 1) & mask;
    }
}

__device__ __forceinline__ int lookup_hash(const unsigned long long* __restrict__ t,
                                           uint32_t key, uint32_t bits, uint32_t mask) {
    uint32_t h = (key * 2654435761u) >> (32u - bits);
    for (uint32_t p = 0; p <= mask; p++) {
        unsigned long long e = t[h];
        if (e == ~0ull) return -1;
        if ((uint32_t)(e >> 32) == key) return (int)(uint32_t)e;
        h = (h + 1) & mask;
    }
    return -1;
}

// ---------------- compaction (sorted path) ----------------

__global__ __launch_bounds__(256)
void count_kernel(const int* __restrict__ grid, int* __restrict__ blockcounts) {
    __shared__ int tot[256];
    int b = blockIdx.x, t = threadIdx.x;
    int cell0 = b * CPB + t * 16;
    int cnt = 0;
#pragma unroll
    for (int j = 0; j < 16; j++) {
        int c = cell0 + j;
        if (c < NCELL && grid[c] >= 0) cnt++;
    }
    tot[t] = cnt;
    __syncthreads();
    if (t < 128) tot[t] += tot[t + 128];
    __syncthreads();
    if (t < 64) {
        int v = tot[t] + tot[t + 64];
#pragma unroll
        for (int d = 32; d > 0; d >>= 1) v += __shfl_down(v, d);
        if (t == 0) blockcounts[b] = v;
    }
}

__global__ __launch_bounds__(256)
void scan_kernel(const int* __restrict__ cnt, int* __restrict__ base) {
    __shared__ int tot[256];
    int t = threadIdx.x;
    int local[PER];
    int s = 0;
#pragma unroll
    for (int j = 0; j < PER; j++) {
        int idx = t * PER + j;
        int v = (idx < NBLK_C) ? cnt[idx] : 0;
        local[j] = s;
        s += v;
    }
    tot[t] = s;
    __syncthreads();
    for (int d = 1; d < 256; d <<= 1) {
        int v = (t >= d) ? tot[t - d] : 0;
        __syncthreads();
        tot[t] += v;
        __syncthreads();
    }
    int tbase = (t == 0) ? 0 : tot[t - 1];
#pragma unroll
    for (int j = 0; j < PER; j++) {
        int idx = t * PER + j;
        if (idx < NBLK_C) base[idx] = tbase + local[j];
    }
}

__global__ __launch_bounds__(256)
void fill_kernel(int* __restrict__ grid, const float* __restrict__ feat,
                 const int* __restrict__ blockbase,
                 int* __restrict__ sorted_orig, int* __restrict__ skeys,
                 float* __restrict__ feat_s) {
    __shared__ int tot[256];
    int b = blockIdx.x, t = threadIdx.x;
    int cell0 = b * CPB + t * 16;
    int myorig[16];
    int cnt = 0;
#pragma unroll
    for (int j = 0; j < 16; j++) {
        int c = cell0 + j;
        int v = (c < NCELL) ? grid[c] : -1;
        myorig[j] = v;
        cnt += (v >= 0) ? 1 : 0;
    }
    tot[t] = cnt;
    __syncthreads();
    for (int d = 1; d < 256; d <<= 1) {
        int v = (t >= d) ? tot[t - d] : 0;
        __syncthreads();
        tot[t] += v;
        __syncthreads();
    }
    int jb = blockbase[b] + ((t == 0) ? 0 : tot[t - 1]);
#pragma unroll
    for (int j = 0; j < 16; j++) {
        int v = myorig[j];
        if (v >= 0) {
            int cell = cell0 + j;
            grid[cell] = jb;                       // dense table now holds RANK
            sorted_orig[jb] = v;
            skeys[jb] = cell;
            const float* fr = feat + (size_t)v * CIN;
            float* fd = feat_s + (size_t)jb * CIN;
            float2 a = *(const float2*)fr;
            float2 bb = *(const float2*)(fr + 2);
            float2 cc = *(const float2*)(fr + 4);
            *(float2*)fd = a;
            *(float2*)(fd + 2) = bb;
            *(float2*)(fd + 4) = cc;
            jb++;
        }
    }
}

// ---------------- W fragment prep (once) ----------------
// K-packing: k = koff*8 + ci (ci<6 real, ci=6,7 zero; koff>=27 zero).
// B-fragment for mfma_f32_16x16x32_bf16: lane l holds B[k = ks*32+(l>>4)*8+b][col = nt*16+(l&15)]
// => koff = ks*4 + (l>>4), ci = b.  Layout: wfrag[(ks*2+nt)*64 + l] as 8 bf16 in a uint4.

__global__ void prep_wfrag(const float* __restrict__ W, uint4* __restrict__ wfrag) {
    int idx = blockIdx.x * blockDim.x + threadIdx.x;
    if (idx >= 7 * 2 * 64) return;
    int l = idx & 63;
    int nt = (idx >> 6) & 1;
    int ks = idx >> 7;
    int koff = ks * 4 + (l >> 4);
    int col = nt * 16 + (l & 15);
    unsigned short v[8];
#pragma unroll
    for (int ci = 0; ci < 8; ci++) {
        float f = 0.f;
        if (ci < CIN && koff < NOFF) f = W[(koff * CIN + ci) * COUT + col];
        v[ci] = f2bf(f);
    }
    uint4 u;
    u.x = (uint32_t)v[0] | ((uint32_t)v[1] << 16);
    u.y = (uint32_t)v[2] | ((uint32_t)v[3] << 16);
    u.z = (uint32_t)v[4] | ((uint32_t)v[5] << 16);
    u.w = (uint32_t)v[6] | ((uint32_t)v[7] << 16);
    wfrag[idx] = u;
}

// ---------------- conv: gather -> fragment-ready LDS -> MFMA, fused stats ----------------

__global__ __launch_bounds__(256)
void conv_mfma(const float* __restrict__ feat_s,
               const int* __restrict__ skeys,
               const int* __restrict__ sorig,
               const uint4* __restrict__ wfrag,
               const int* __restrict__ grid_tab, int N,
               float* __restrict__ out,
               float* __restrict__ stats_g) {
    __shared__ uint4 Alds[4 * 7 * 64];   // 28672 B: [site-group][kstep][lane-slot]
    __shared__ uint4 Wlds[7 * 2 * 64];   // 14336 B
    __shared__ float bstat[64];          // [sum c0..31 | sq c0..31]

    int tid = threadIdx.x;
    int w = tid >> 6, l = tid & 63;

    for (int t = tid; t < 7 * 2 * 64; t += 256) Wlds[t] = wfrag[t];
    if (tid < 64) bstat[tid] = 0.f;

    int b = xcd_swizzle(blockIdx.x, gridDim.x);
    int bs = b * 64;
    int site = bs + l;                   // gather: lane l owns site l of the block
    int key = (site < N) ? skeys[site] : -1;
    uint32_t uk = (uint32_t)(key < 0 ? 0 : key);
    int x = (int)(uk / (GRIDX * GRIDX));
    int rem = (int)(uk % (GRIDX * GRIDX));
    int y = rem / GRIDX;
    int z = rem % GRIDX;

#pragma unroll
    for (int it = 0; it < 7; it++) {
        int koff = w + 4 * it;           // 0..27 (27 = zero-pad region)
        int dxl = koff / 9 - 1, dyl = (koff / 3) % 3 - 1, dzl = koff % 3 - 1;
        int nx = x + dxl, ny = y + dyl, nz = z + dzl;
        bool ok = (koff < NOFF) && (key >= 0) &&
                  ((unsigned)nx < GRIDX) && ((unsigned)ny < GRIDX) && ((unsigned)nz < GRIDX);
        int nkey = key + dxl * (GRIDX * GRIDX) + dyl * GRIDX + dzl;
        nkey = min(max(nkey, 0), NCELL - 1);
        int pos = grid_tab[nkey];        // unconditional: table always valid
        pos = ok ? pos : -1;
        uint4 val = make_uint4(0u, 0u, 0u, 0u);
        if (pos >= 0) {
            const float2* fp = (const float2*)(feat_s + (size_t)pos * CIN);
            float2 f0 = fp[0], f1 = fp[1], f2 = fp[2];
            val.x = (uint32_t)f2bf(f0.x) | ((uint32_t)f2bf(f0.y) << 16);
            val.y = (uint32_t)f2bf(f1.x) | ((uint32_t)f2bf(f1.y) << 16);
            val.z = (uint32_t)f2bf(f2.x) | ((uint32_t)f2bf(f2.y) << 16);
        }
        // A slot: sg=l>>4, ks=koff>>2, lane' = (koff&3)*16 + (l&15)
        int slot = ((l >> 4) * 7 + (koff >> 2)) * 64 + (koff & 3) * 16 + (l & 15);
        Alds[slot] = val;
    }
    __syncthreads();

    f32x4 acc0 = {0.f, 0.f, 0.f, 0.f};
    f32x4 acc1 = {0.f, 0.f, 0.f, 0.f};
#pragma unroll
    for (int ks = 0; ks < 7; ks++) {
        short8 a  = *(const short8*)&Alds[(w * 7 + ks) * 64 + l];
        short8 b0 = *(const short8*)&Wlds[(ks * 2 + 0) * 64 + l];
        short8 b1 = *(const short8*)&Wlds[(ks * 2 + 1) * 64 + l];
        acc0 = __builtin_amdgcn_mfma_f32_16x16x32_bf16(a, b0, acc0, 0, 0, 0);
        acc1 = __builtin_amdgcn_mfma_f32_16x16x32_bf16(a, b1, acc1, 0, 0, 0);
    }

    // store: C/D map col=lane&15, row=(lane>>4)*4+r  (verified m89/m91)
    int col = l & 15;
    int rg = l >> 4;
#pragma unroll
    for (int r = 0; r < 4; r++) {
        int sr = bs + w * 16 + rg * 4 + r;
        if (sr < N) {
            size_t o = (size_t)sorig[sr] * COUT;
            out[o + col] = acc0[r];
            out[o + 16 + col] = acc1[r];
        }
    }

    // fused BN stats (pre-norm sums); invalid sites contribute exact zeros
    float s0 = acc0[0] + acc0[1] + acc0[2] + acc0[3];
    float q0 = acc0[0]*acc0[0] + acc0[1]*acc0[1] + acc0[2]*acc0[2] + acc0[3]*acc0[3];
    float s1 = acc1[0] + acc1[1] + acc1[2] + acc1[3];
    float q1 = acc1[0]*acc1[0] + acc1[1]*acc1[1] + acc1[2]*acc1[2] + acc1[3]*acc1[3];
    s0 += __shfl_xor(s0, 16); s0 += __shfl_xor(s0, 32);
    q0 += __shfl_xor(q0, 16); q0 += __shfl_xor(q0, 32);
    s1 += __shfl_xor(s1, 16); s1 += __shfl_xor(s1, 32);
    q1 += __shfl_xor(q1, 16); q1 += __shfl_xor(q1, 32);
    if (l < 16) {
        atomicAdd(&bstat[col], s0);
        atomicAdd(&bstat[16 + col], s1);
        atomicAdd(&bstat[32 + col], q0);
        atomicAdd(&bstat[48 + col], q1);
    }
    __syncthreads();
    if (tid < 64) {
        int slice = blockIdx.x & 63;
        atomicAdd(&stats_g[slice * 64 + tid], bstat[tid]);
    }
}

// ---------------- BN finalize / norm ----------------

__global__ void finalize_sliced(const float* __restrict__ stats_g,
                                const float* __restrict__ gamma,
                                const float* __restrict__ beta,
                                float invN, float* __restrict__ scsh) {
    int c = threadIdx.x;
    if (c < COUT) {
        float s = 0.f, q = 0.f;
        for (int sl = 0; sl < 64; sl++) {
            s += stats_g[sl * 64 + c];
            q += stats_g[sl * 64 + 32 + c];
        }
        float mean = s * invN;
        float var = q * invN - mean * mean;
        float sc = gamma[c] * rsqrtf(var + BN_EPS);
        scsh[c] = sc;
        scsh[COUT + c] = beta[c] - mean * sc;
    }
}

__global__ __launch_bounds__(256)
void norm_kernel(float* __restrict__ out, long total_vec,
                 const float* __restrict__ scaleshift) {
    __shared__ float sc[COUT], sh[COUT];
    for (int t = threadIdx.x; t < COUT; t += blockDim.x) {
        sc[t] = scaleshift[t];
        sh[t] = scaleshift[COUT + t];
    }
    __syncthreads();
    long stride = (long)gridDim.x * blockDim.x;
    float4* p = (float4*)out;
    for (long v = (long)blockIdx.x * blockDim.x + threadIdx.x; v < total_vec; v += stride) {
        int cbase = (int)(v & 7) * 4;
        float4 u = p[v];
        u.x = fmaxf(u.x * sc[cbase + 0] + sh[cbase + 0], 0.f);
        u.y = fmaxf(u.y * sc[cbase + 1] + sh[cbase + 1], 0.f);
        u.z = fmaxf(u.z * sc[cbase + 2] + sh[cbase + 2], 0.f);
        u.w = fmaxf(u.w * sc[cbase + 3] + sh[cbase + 3], 0.f);
        p[v] = u;
    }
}

// ---------------- fallback path kernels (R2) ----------------

template <bool DENSE>
__global__ __launch_bounds__(256)
void conv_kernel(const float* __restrict__ feat,
                 const int* __restrict__ coords,
                 const float* __restrict__ W,
                 const void* __restrict__ table,
                 uint32_t bits, uint32_t mask, int N,
                 float* __restrict__ out) {
    __shared__ __align__(16) float wlds[NOFF * CIN * COUT];
    for (int t = threadIdx.x; t < NOFF * CIN * COUT; t += blockDim.x)
        wlds[t] = W[t];
    __syncthreads();

    int i = blockIdx.x * blockDim.x + threadIdx.x;
    if (i >= N) return;
    int x = coords[3 * i], y = coords[3 * i + 1], z = coords[3 * i + 2];

    float acc[COUT];
#pragma unroll
    for (int c = 0; c < COUT; c++) acc[c] = 0.f;

#pragma unroll 1
    for (int k = 0; k < NOFF; k++) {
        int dx = k / 9 - 1, dy = (k / 3) % 3 - 1, dz = k % 3 - 1;
        int nx = x + dx, ny = y + dy, nz = z + dz;
        int idx = -1;
        if ((unsigned)nx < GRIDX && (unsigned)ny < GRIDX && (unsigned)nz < GRIDX) {
            uint32_t key = (uint32_t)((nx * GRIDX + ny) * GRIDX + nz);
            if (DENSE) idx = ((const int*)table)[key];
            else       idx = lookup_hash((const unsigned long long*)table, key, bits, mask);
        }
        if (idx >= 0) {
            const float* fr = feat + (size_t)idx * CIN;
            float2 a = *(const float2*)(fr);
            float2 b = *(const float2*)(fr + 2);
            float2 c2 = *(const float2*)(fr + 4);
            float f[CIN] = {a.x, a.y, b.x, b.y, c2.x, c2.y};
            const float* wk = &wlds[k * CIN * COUT];
#pragma unroll
            for (int ci = 0; ci < CIN; ci++) {
                const float4* w4 = (const float4*)(wk + ci * COUT);
                float fv = f[ci];
#pragma unroll
                for (int q = 0; q < COUT / 4; q++) {
                    float4 wv = w4[q];
                    acc[4 * q + 0] += fv * wv.x;
                    acc[4 * q + 1] += fv * wv.y;
                    acc[4 * q + 2] += fv * wv.z;
                    acc[4 * q + 3] += fv * wv.w;
                }
            }
        }
    }

    float4* op = (float4*)(out + (size_t)i * COUT);
#pragma unroll
    for (int q = 0; q < COUT / 4; q++) {
        float4 v;
        v.x = acc[4 * q + 0];
        v.y = acc[4 * q + 1];
        v.z = acc[4 * q + 2];
        v.w = acc[4 * q + 3];
        op[q] = v;
    }
}

__global__ __launch_bounds__(256)
void stats_kernel(const float* __restrict__ out, long total_vec,
                  float* __restrict__ stats) {
    __shared__ float lsum[COUT], lsq[COUT];
    for (int t = threadIdx.x; t < COUT; t += blockDim.x) { lsum[t] = 0.f; lsq[t] = 0.f; }
    __syncthreads();

    long stride = (long)gridDim.x * blockDim.x;
    long v0 = (long)blockIdx.x * blockDim.x + threadIdx.x;
    int cbase = (int)(v0 & 7) * 4;
    float s[4] = {0, 0, 0, 0}, q[4] = {0, 0, 0, 0};
    const float4* p = (const float4*)out;
    for (long v = v0; v < total_vec; v += stride) {
        float4 u = p[v];
        s[0] += u.x; q[0] += u.x * u.x;
        s[1] += u.y; q[1] += u.y * u.y;
        s[2] += u.z; q[2] += u.z * u.z;
        s[3] += u.w; q[3] += u.w * u.w;
    }
#pragma unroll
    for (int j = 0; j < 4; j++) {
        atomicAdd(&lsum[cbase + j], s[j]);
        atomicAdd(&lsq[cbase + j], q[j]);
    }
    __syncthreads();
    for (int t = threadIdx.x; t < COUT; t += blockDim.x) {
        atomicAdd(&stats[t], lsum[t]);
        atomicAdd(&stats[COUT + t], lsq[t]);
    }
}

__global__ void finalize_flat(const float* __restrict__ stats,
                              const float* __restrict__ gamma,
                              const float* __restrict__ beta,
                              float invN, float* __restrict__ scaleshift) {
    int c = threadIdx.x;
    if (c < COUT) {
        float mean = stats[c] * invN;
        float var = stats[COUT + c] * invN - mean * mean;
        float sc = gamma[c] * rsqrtf(var + BN_EPS);
        scaleshift[c] = sc;
        scaleshift[COUT + c] = beta[c] - mean * sc;
    }
}

// ---------------- launch ----------------

extern "C" void kernel_launch(void* const* d_in, const int* in_sizes, int n_in,
                              void* d_out, int out_size, void* d_ws, size_t ws_size,
                              hipStream_t stream) {
    const float* feat   = (const float*)d_in[0];
    const int*   coords = (const int*)d_in[1];
    const float* W      = (const float*)d_in[2];
    const float* gamma  = (const float*)d_in[3];
    const float* beta   = (const float*)d_in[4];
    float* out = (float*)d_out;

    int N = in_sizes[0] / CIN;
    const int threads = 256;
    int blocksN = (N + threads - 1) / threads;
    long total_vec = (long)N * COUT / 4;

    size_t a256 = 255;
    size_t table_b   = (size_t)NCELL * 4;                     // 32 MB
    size_t off_sorig = (table_b + a256) & ~a256;
    size_t off_skeys = (off_sorig + (size_t)N * 4 + a256) & ~a256;
    size_t off_feats = (off_skeys + (size_t)N * 4 + a256) & ~a256;
    size_t off_bcnt  = (off_feats + (size_t)N * CIN * 4 + a256) & ~a256;
    size_t off_bbase = (off_bcnt + (size_t)NBLK_C * 4 + a256) & ~a256;
    size_t off_wfrag = (off_bbase + (size_t)NBLK_C * 4 + a256) & ~a256;
    size_t off_stats = (off_wfrag + (size_t)(7 * 2 * 64) * 16 + a256) & ~a256;
    size_t off_scsh  = off_stats + (size_t)64 * 64 * 4;
    size_t need_sorted = off_scsh + 2 * COUT * sizeof(float) + 256;

    if (ws_size >= need_sorted) {
        int*   grid  = (int*)d_ws;
        int*   sorig = (int*)((char*)d_ws + off_sorig);
        int*   skeys = (int*)((char*)d_ws + off_skeys);
        float* feats = (float*)((char*)d_ws + off_feats);
        int*   bcnt  = (int*)((char*)d_ws + off_bcnt);
        int*   bbase = (int*)((char*)d_ws + off_bbase);
        uint4* wfrag = (uint4*)((char*)d_ws + off_wfrag);
        float* stats = (float*)((char*)d_ws + off_stats);
        float* scsh  = (float*)((char*)d_ws + off_scsh);

        hipMemsetAsync(d_ws, 0xFF, table_b, stream);
        hipMemsetAsync(stats, 0, (size_t)64 * 64 * 4, stream);
        prep_wfrag<<<4, threads, 0, stream>>>(W, wfrag);
        build_dense<<<blocksN, threads, 0, stream>>>(coords, N, grid);
        count_kernel<<<NBLK_C, threads, 0, stream>>>(grid, bcnt);
        scan_kernel<<<1, threads, 0, stream>>>(bcnt, bbase);
        fill_kernel<<<NBLK_C, threads, 0, stream>>>(grid, feat, bbase, sorig, skeys, feats);
        int cblocks = (N + 63) / 64;
        conv_mfma<<<cblocks, threads, 0, stream>>>(feats, skeys, sorig, wfrag, grid, N, out, stats);
        finalize_sliced<<<1, 64, 0, stream>>>(stats, gamma, beta, 1.0f / (float)N, scsh);
        norm_kernel<<<2048, threads, 0, stream>>>(out, total_vec, scsh);
        return;
    }

    // ---------- fallback (R2 behavior) ----------
    size_t dense_bytes = table_b;
    bool dense = (ws_size >= dense_bytes + 512);
    size_t table_bytes;
    uint32_t bits = 22, mask = 0;
    if (dense) {
        table_bytes = dense_bytes;
    } else {
        while (bits > 20 && ((size_t)8 << bits) + 512 > ws_size) bits--;
        table_bytes = (size_t)8 << bits;
        mask = (1u << bits) - 1u;
    }
    float* stats = (float*)d_ws;
    float* scsh  = stats + 2 * COUT;

    hipMemsetAsync(d_ws, 0xFF, table_bytes, stream);
    if (dense) {
        build_dense<<<blocksN, threads, 0, stream>>>(coords, N, (int*)d_ws);
        conv_kernel<true><<<blocksN, threads, 0, stream>>>(feat, coords, W, d_ws, 0, 0, N, out);
    } else {
        build_hash<<<blocksN, threads, 0, stream>>>(coords, N, (unsigned long long*)d_ws, bits, mask);
        conv_kernel<false><<<blocksN, threads, 0, stream>>>(feat, coords, W, d_ws, bits, mask, N, out);
    }
    hipMemsetAsync(stats, 0, 2 * COUT * sizeof(float), stream);
    stats_kernel<<<1024, threads, 0, stream>>>(out, total_vec, stats);
    finalize_flat<<<1, 64, 0, stream>>>(stats, gamma, beta, 1.0f / (float)N, scsh);
    norm_kernel<<<2048, threads, 0, stream>>>(out, total_vec, scsh);
}

// Round 5
// 243.819 us; speedup vs baseline: 2.3577x; 1.2230x over previous
//
#include <hip/hip_runtime.h>
#include <stdint.h>

#define GRIDX 200
#define NCELL (GRIDX * GRIDX * GRIDX)          // 8,000,000
#define CIN 6
#define COUT 32
#define NOFF 27
#define BN_EPS 1e-5f
#define CPB 4096                                // cells per compaction block
#define NBLK_C ((NCELL + CPB - 1) / CPB)        // 1954
#define PER 8                                   // scan items/thread

typedef __attribute__((ext_vector_type(8))) short short8;
typedef __attribute__((ext_vector_type(4))) float f32x4;

// ---------------- helpers ----------------

__device__ __forceinline__ int xcd_swizzle(int b, int nwg) {
    int q = nwg >> 3, r = nwg & 7;
    int xcd = b & 7, idx = b >> 3;
    int base = (xcd < r) ? xcd * (q + 1) : r * (q + 1) + (xcd - r) * q;
    return base + idx;
}

__device__ __forceinline__ unsigned short f2bf(float f) {
    uint32_t u = __float_as_uint(f);
    return (unsigned short)((u + 0x7FFFu + ((u >> 16) & 1u)) >> 16);   // RNE
}

// ---------------- table build ----------------

__global__ void build_dense(const int* __restrict__ coords, int N, int* __restrict__ grid) {
    int i = blockIdx.x * blockDim.x + threadIdx.x;
    if (i >= N) return;
    int x = coords[3 * i], y = coords[3 * i + 1], z = coords[3 * i + 2];
    grid[(x * GRIDX + y) * GRIDX + z] = i;
}

__global__ void build_hash(const int* __restrict__ coords, int N,
                           unsigned long long* __restrict__ table,
                           uint32_t bits, uint32_t mask) {
    int i = blockIdx.x * blockDim.x + threadIdx.x;
    if (i >= N) return;
    int x = coords[3 * i], y = coords[3 * i + 1], z = coords[3 * i + 2];
    uint32_t key = (uint32_t)((x * GRIDX + y) * GRIDX + z);
    unsigned long long packed = ((unsigned long long)key << 32) | (uint32_t)i;
    uint32_t h = (key * 2654435761u) >> (32u - bits);
    for (uint32_t p = 0; p <= mask; p++) {
        unsigned long long prev = atomicCAS(&table[h], ~0ull, packed);
        if (prev == ~0ull) return;
        h = (h + 1) & mask;
    }
}

__device__ __forceinline__ int lookup_hash(const unsigned long long* __restrict__ t,
                                           uint32_t key, uint32_t bits, uint32_t mask) {
    uint32_t h = (key * 2654435761u) >> (32u - bits);
    for (uint32_t p = 0; p <= mask; p++) {
        unsigned long long e = t[h];
        if (e == ~0ull) return -1;
        if ((uint32_t)(e >> 32) == key) return (int)(uint32_t)e;
        h = (h + 1) & mask;
    }
    return -1;
}

// ---------------- compaction (sorted path) ----------------

__global__ __launch_bounds__(256)
void count_kernel(const int* __restrict__ grid, int* __restrict__ blockcounts) {
    __shared__ int tot[256];
    int b = blockIdx.x, t = threadIdx.x;
    int cell0 = b * CPB + t * 16;
    int cnt = 0;
#pragma unroll
    for (int j = 0; j < 16; j++) {
        int c = cell0 + j;
        if (c < NCELL && grid[c] >= 0) cnt++;
    }
    tot[t] = cnt;
    __syncthreads();
    if (t < 128) tot[t] += tot[t + 128];
    __syncthreads();
    if (t < 64) {
        int v = tot[t] + tot[t + 64];
#pragma unroll
        for (int d = 32; d > 0; d >>= 1) v += __shfl_down(v, d);
        if (t == 0) blockcounts[b] = v;
    }
}

__global__ __launch_bounds__(256)
void scan_kernel(const int* __restrict__ cnt, int* __restrict__ base) {
    __shared__ int tot[256];
    int t = threadIdx.x;
    int local[PER];
    int s = 0;
#pragma unroll
    for (int j = 0; j < PER; j++) {
        int idx = t * PER + j;
        int v = (idx < NBLK_C) ? cnt[idx] : 0;
        local[j] = s;
        s += v;
    }
    tot[t] = s;
    __syncthreads();
    for (int d = 1; d < 256; d <<= 1) {
        int v = (t >= d) ? tot[t - d] : 0;
        __syncthreads();
        tot[t] += v;
        __syncthreads();
    }
    int tbase = (t == 0) ? 0 : tot[t - 1];
#pragma unroll
    for (int j = 0; j < PER; j++) {
        int idx = t * PER + j;
        if (idx < NBLK_C) base[idx] = tbase + local[j];
    }
}

// fill: compact grid -> ranks; emit bf16x8 feature rows (16B, ci=6,7 zero)
__global__ __launch_bounds__(256)
void fill_kernel(int* __restrict__ grid, const float* __restrict__ feat,
                 const int* __restrict__ blockbase,
                 int* __restrict__ sorted_orig, int* __restrict__ skeys,
                 uint4* __restrict__ feat_bf) {
    __shared__ int tot[256];
    int b = blockIdx.x, t = threadIdx.x;
    int cell0 = b * CPB + t * 16;
    int myorig[16];
    int cnt = 0;
#pragma unroll
    for (int j = 0; j < 16; j++) {
        int c = cell0 + j;
        int v = (c < NCELL) ? grid[c] : -1;
        myorig[j] = v;
        cnt += (v >= 0) ? 1 : 0;
    }
    tot[t] = cnt;
    __syncthreads();
    for (int d = 1; d < 256; d <<= 1) {
        int v = (t >= d) ? tot[t - d] : 0;
        __syncthreads();
        tot[t] += v;
        __syncthreads();
    }
    int jb = blockbase[b] + ((t == 0) ? 0 : tot[t - 1]);
#pragma unroll
    for (int j = 0; j < 16; j++) {
        int v = myorig[j];
        if (v >= 0) {
            int cell = cell0 + j;
            grid[cell] = jb;                       // dense table now holds RANK
            sorted_orig[jb] = v;
            skeys[jb] = cell;
            const float* fr = feat + (size_t)v * CIN;
            float2 a = *(const float2*)fr;
            float2 bb = *(const float2*)(fr + 2);
            float2 cc = *(const float2*)(fr + 4);
            uint4 u;
            u.x = (uint32_t)f2bf(a.x) | ((uint32_t)f2bf(a.y) << 16);
            u.y = (uint32_t)f2bf(bb.x) | ((uint32_t)f2bf(bb.y) << 16);
            u.z = (uint32_t)f2bf(cc.x) | ((uint32_t)f2bf(cc.y) << 16);
            u.w = 0u;
            feat_bf[jb] = u;
            jb++;
        }
    }
}

// ---------------- W fragment prep (once) ----------------
// K-packing: k = koff*8 + ci (ci<6 real, ci=6,7 zero; koff>=27 zero).
// B-fragment (16x16x32 bf16): lane l holds B[k = ks*32+(l>>4)*8+b][col = nt*16+(l&15)]
// Layout: wfrag[(ks*2+nt)*64 + l] = 8 bf16.

__global__ void prep_wfrag(const float* __restrict__ W, uint4* __restrict__ wfrag) {
    int idx = blockIdx.x * blockDim.x + threadIdx.x;
    if (idx >= 7 * 2 * 64) return;
    int l = idx & 63;
    int nt = (idx >> 6) & 1;
    int ks = idx >> 7;
    int koff = ks * 4 + (l >> 4);
    int col = nt * 16 + (l & 15);
    unsigned short v[8];
#pragma unroll
    for (int ci = 0; ci < 8; ci++) {
        float f = 0.f;
        if (ci < CIN && koff < NOFF) f = W[(koff * CIN + ci) * COUT + col];
        v[ci] = f2bf(f);
    }
    uint4 u;
    u.x = (uint32_t)v[0] | ((uint32_t)v[1] << 16);
    u.y = (uint32_t)v[2] | ((uint32_t)v[3] << 16);
    u.z = (uint32_t)v[4] | ((uint32_t)v[5] << 16);
    u.w = (uint32_t)v[6] | ((uint32_t)v[7] << 16);
    wfrag[idx] = u;
}

// ---------------- conv: gather -> LDS -> MFMA, fused stats, transposed stores ----------------

__global__ __launch_bounds__(256)
void conv_mfma(const uint4* __restrict__ feat_bf,      // N+1 rows (row N = zeros)
               const int* __restrict__ skeys,
               const int* __restrict__ sorig,
               const uint4* __restrict__ wfrag,
               const int* __restrict__ grid_tab, int N,
               float* __restrict__ out,
               float* __restrict__ stats_g) {
    __shared__ uint4 Alds[4 * 7 * 64];   // 28672 B; reused as Clds[64][36] f32 (9216 B)
    __shared__ float bstat[64];

    int tid = threadIdx.x;
    int w = tid >> 6, l = tid & 63;

    if (tid < 64) bstat[tid] = 0.f;

    // B fragments in registers (coalesced 1KB loads, L1-resident after first block)
    const short8* wf8 = (const short8*)wfrag;
    short8 bf0[7], bf1[7];
#pragma unroll
    for (int ks = 0; ks < 7; ks++) {
        bf0[ks] = wf8[(ks * 2 + 0) * 64 + l];
        bf1[ks] = wf8[(ks * 2 + 1) * 64 + l];
    }

    int b = xcd_swizzle(blockIdx.x, gridDim.x);
    int bs = b * 64;
    int site = bs + l;                   // gather: lane l owns site l of the block
    int key = (site < N) ? skeys[site] : -1;
    uint32_t uk = (uint32_t)(key < 0 ? 0 : key);
    int x = (int)(uk / (GRIDX * GRIDX));
    int rem = (int)(uk % (GRIDX * GRIDX));
    int y = rem / GRIDX;
    int z = rem % GRIDX;

#pragma unroll
    for (int it = 0; it < 7; it++) {
        int koff = w + 4 * it;           // 0..27 (27 = zero-pad region)
        int dxl = koff / 9 - 1, dyl = (koff / 3) % 3 - 1, dzl = koff % 3 - 1;
        int nx = x + dxl, ny = y + dyl, nz = z + dzl;
        bool ok = (koff < NOFF) && (key >= 0) &&
                  ((unsigned)nx < GRIDX) && ((unsigned)ny < GRIDX) && ((unsigned)nz < GRIDX);
        int nkey = key + dxl * (GRIDX * GRIDX) + dyl * GRIDX + dzl;
        nkey = min(max(nkey, 0), NCELL - 1);
        int pos = grid_tab[nkey];        // unconditional: table always valid
        pos = (ok && pos >= 0) ? pos : N;  // miss -> zero row (branch-free)
        uint4 val = feat_bf[pos];
        // A slot: sg=l>>4, ks=koff>>2, lane' = (koff&3)*16 + (l&15)
        int slot = ((l >> 4) * 7 + (koff >> 2)) * 64 + (koff & 3) * 16 + (l & 15);
        Alds[slot] = val;
    }
    __syncthreads();

    f32x4 acc0 = {0.f, 0.f, 0.f, 0.f};
    f32x4 acc1 = {0.f, 0.f, 0.f, 0.f};
    const short8* A8 = (const short8*)Alds;
#pragma unroll
    for (int ks = 0; ks < 7; ks++) {
        short8 a = A8[(w * 7 + ks) * 64 + l];
        acc0 = __builtin_amdgcn_mfma_f32_16x16x32_bf16(a, bf0[ks], acc0, 0, 0, 0);
        acc1 = __builtin_amdgcn_mfma_f32_16x16x32_bf16(a, bf1[ks], acc1, 0, 0, 0);
    }

    // fused BN stats (pre-norm); invalid sites contribute exact zeros
    float s0 = acc0[0] + acc0[1] + acc0[2] + acc0[3];
    float q0 = acc0[0]*acc0[0] + acc0[1]*acc0[1] + acc0[2]*acc0[2] + acc0[3]*acc0[3];
    float s1 = acc1[0] + acc1[1] + acc1[2] + acc1[3];
    float q1 = acc1[0]*acc1[0] + acc1[1]*acc1[1] + acc1[2]*acc1[2] + acc1[3]*acc1[3];
    s0 += __shfl_xor(s0, 16); s0 += __shfl_xor(s0, 32);
    q0 += __shfl_xor(q0, 16); q0 += __shfl_xor(q0, 32);
    s1 += __shfl_xor(s1, 16); s1 += __shfl_xor(s1, 32);
    q1 += __shfl_xor(q1, 16); q1 += __shfl_xor(q1, 32);
    int col = l & 15;
    int rg = l >> 4;
    if (l < 16) {
        atomicAdd(&bstat[col], s0);
        atomicAdd(&bstat[16 + col], s1);
        atomicAdd(&bstat[32 + col], q0);
        atomicAdd(&bstat[48 + col], q1);
    }
    __syncthreads();                     // bstat done AND all A-reads done
    if (tid < 64) {
        int slice = blockIdx.x & 63;
        atomicAdd(&stats_g[slice * 64 + tid], bstat[tid]);
    }

    // transpose C via LDS (reuse Alds space), stride 36 floats (16B-aligned chunks)
    float* Clds = (float*)Alds;
#pragma unroll
    for (int r = 0; r < 4; r++) {
        int s = w * 16 + rg * 4 + r;     // C/D map: col=lane&15, row=(lane>>4)*4+r
        Clds[s * 36 + col] = acc0[r];
        Clds[s * 36 + col + 16] = acc1[r];
    }
    __syncthreads();

    int st = tid >> 2;                   // site-local 0..63
    int q = (tid & 3) * 2;               // chunk pair
    int sr = bs + st;
    if (sr < N) {
        float4* gp = (float4*)(out + (size_t)sorig[sr] * COUT + q * 4);
        gp[0] = *(const float4*)&Clds[st * 36 + q * 4];
        gp[1] = *(const float4*)&Clds[st * 36 + q * 4 + 4];
    }
}

// ---------------- BN finalize / norm ----------------

__global__ void finalize_sliced(const float* __restrict__ stats_g,
                                const float* __restrict__ gamma,
                                const float* __restrict__ beta,
                                float invN, float* __restrict__ scsh) {
    int c = threadIdx.x;
    if (c < COUT) {
        float s = 0.f, q = 0.f;
        for (int sl = 0; sl < 64; sl++) {
            s += stats_g[sl * 64 + c];
            q += stats_g[sl * 64 + 32 + c];
        }
        float mean = s * invN;
        float var = q * invN - mean * mean;
        float sc = gamma[c] * rsqrtf(var + BN_EPS);
        scsh[c] = sc;
        scsh[COUT + c] = beta[c] - mean * sc;
    }
}

__global__ __launch_bounds__(256)
void norm_kernel(float* __restrict__ out, long total_vec,
                 const float* __restrict__ scaleshift) {
    __shared__ float sc[COUT], sh[COUT];
    for (int t = threadIdx.x; t < COUT; t += blockDim.x) {
        sc[t] = scaleshift[t];
        sh[t] = scaleshift[COUT + t];
    }
    __syncthreads();
    long stride = (long)gridDim.x * blockDim.x;
    float4* p = (float4*)out;
    for (long v = (long)blockIdx.x * blockDim.x + threadIdx.x; v < total_vec; v += stride) {
        int cbase = (int)(v & 7) * 4;
        float4 u = p[v];
        u.x = fmaxf(u.x * sc[cbase + 0] + sh[cbase + 0], 0.f);
        u.y = fmaxf(u.y * sc[cbase + 1] + sh[cbase + 1], 0.f);
        u.z = fmaxf(u.z * sc[cbase + 2] + sh[cbase + 2], 0.f);
        u.w = fmaxf(u.w * sc[cbase + 3] + sh[cbase + 3], 0.f);
        p[v] = u;
    }
}

// ---------------- fallback path kernels (R2) ----------------

template <bool DENSE>
__global__ __launch_bounds__(256)
void conv_kernel(const float* __restrict__ feat,
                 const int* __restrict__ coords,
                 const float* __restrict__ W,
                 const void* __restrict__ table,
                 uint32_t bits, uint32_t mask, int N,
                 float* __restrict__ out) {
    __shared__ __align__(16) float wlds[NOFF * CIN * COUT];
    for (int t = threadIdx.x; t < NOFF * CIN * COUT; t += blockDim.x)
        wlds[t] = W[t];
    __syncthreads();

    int i = blockIdx.x * blockDim.x + threadIdx.x;
    if (i >= N) return;
    int x = coords[3 * i], y = coords[3 * i + 1], z = coords[3 * i + 2];

    float acc[COUT];
#pragma unroll
    for (int c = 0; c < COUT; c++) acc[c] = 0.f;

#pragma unroll 1
    for (int k = 0; k < NOFF; k++) {
        int dx = k / 9 - 1, dy = (k / 3) % 3 - 1, dz = k % 3 - 1;
        int nx = x + dx, ny = y + dy, nz = z + dz;
        int idx = -1;
        if ((unsigned)nx < GRIDX && (unsigned)ny < GRIDX && (unsigned)nz < GRIDX) {
            uint32_t key = (uint32_t)((nx * GRIDX + ny) * GRIDX + nz);
            if (DENSE) idx = ((const int*)table)[key];
            else       idx = lookup_hash((const unsigned long long*)table, key, bits, mask);
        }
        if (idx >= 0) {
            const float* fr = feat + (size_t)idx * CIN;
            float2 a = *(const float2*)(fr);
            float2 b = *(const float2*)(fr + 2);
            float2 c2 = *(const float2*)(fr + 4);
            float f[CIN] = {a.x, a.y, b.x, b.y, c2.x, c2.y};
            const float* wk = &wlds[k * CIN * COUT];
#pragma unroll
            for (int ci = 0; ci < CIN; ci++) {
                const float4* w4 = (const float4*)(wk + ci * COUT);
                float fv = f[ci];
#pragma unroll
                for (int q = 0; q < COUT / 4; q++) {
                    float4 wv = w4[q];
                    acc[4 * q + 0] += fv * wv.x;
                    acc[4 * q + 1] += fv * wv.y;
                    acc[4 * q + 2] += fv * wv.z;
                    acc[4 * q + 3] += fv * wv.w;
                }
            }
        }
    }

    float4* op = (float4*)(out + (size_t)i * COUT);
#pragma unroll
    for (int q = 0; q < COUT / 4; q++) {
        float4 v;
        v.x = acc[4 * q + 0];
        v.y = acc[4 * q + 1];
        v.z = acc[4 * q + 2];
        v.w = acc[4 * q + 3];
        op[q] = v;
    }
}

__global__ __launch_bounds__(256)
void stats_kernel(const float* __restrict__ out, long total_vec,
                  float* __restrict__ stats) {
    __shared__ float lsum[COUT], lsq[COUT];
    for (int t = threadIdx.x; t < COUT; t += blockDim.x) { lsum[t] = 0.f; lsq[t] = 0.f; }
    __syncthreads();

    long stride = (long)gridDim.x * blockDim.x;
    long v0 = (long)blockIdx.x * blockDim.x + threadIdx.x;
    int cbase = (int)(v0 & 7) * 4;
    float s[4] = {0, 0, 0, 0}, q[4] = {0, 0, 0, 0};
    const float4* p = (const float4*)out;
    for (long v = v0; v < total_vec; v += stride) {
        float4 u = p[v];
        s[0] += u.x; q[0] += u.x * u.x;
        s[1] += u.y; q[1] += u.y * u.y;
        s[2] += u.z; q[2] += u.z * u.z;
        s[3] += u.w; q[3] += u.w * u.w;
    }
#pragma unroll
    for (int j = 0; j < 4; j++) {
        atomicAdd(&lsum[cbase + j], s[j]);
        atomicAdd(&lsq[cbase + j], q[j]);
    }
    __syncthreads();
    for (int t = threadIdx.x; t < COUT; t += blockDim.x) {
        atomicAdd(&stats[t], lsum[t]);
        atomicAdd(&stats[COUT + t], lsq[t]);
    }
}

__global__ void finalize_flat(const float* __restrict__ stats,
                              const float* __restrict__ gamma,
                              const float* __restrict__ beta,
                              float invN, float* __restrict__ scaleshift) {
    int c = threadIdx.x;
    if (c < COUT) {
        float mean = stats[c] * invN;
        float var = stats[COUT + c] * invN - mean * mean;
        float sc = gamma[c] * rsqrtf(var + BN_EPS);
        scaleshift[c] = sc;
        scaleshift[COUT + c] = beta[c] - mean * sc;
    }
}

// ---------------- launch ----------------

extern "C" void kernel_launch(void* const* d_in, const int* in_sizes, int n_in,
                              void* d_out, int out_size, void* d_ws, size_t ws_size,
                              hipStream_t stream) {
    const float* feat   = (const float*)d_in[0];
    const int*   coords = (const int*)d_in[1];
    const float* W      = (const float*)d_in[2];
    const float* gamma  = (const float*)d_in[3];
    const float* beta   = (const float*)d_in[4];
    float* out = (float*)d_out;

    int N = in_sizes[0] / CIN;
    const int threads = 256;
    int blocksN = (N + threads - 1) / threads;
    long total_vec = (long)N * COUT / 4;

    size_t a256 = 255;
    size_t table_b    = (size_t)NCELL * 4;                     // 32 MB
    size_t off_sorig  = (table_b + a256) & ~a256;
    size_t off_skeys  = (off_sorig + (size_t)N * 4 + a256) & ~a256;
    size_t off_featbf = (off_skeys + (size_t)N * 4 + a256) & ~a256;
    size_t off_bcnt   = (off_featbf + (size_t)(N + 1) * 16 + a256) & ~a256;
    size_t off_bbase  = (off_bcnt + (size_t)NBLK_C * 4 + a256) & ~a256;
    size_t off_wfrag  = (off_bbase + (size_t)NBLK_C * 4 + a256) & ~a256;
    size_t off_stats  = (off_wfrag + (size_t)(7 * 2 * 64) * 16 + a256) & ~a256;
    size_t off_scsh   = off_stats + (size_t)64 * 64 * 4;
    size_t need_sorted = off_scsh + 2 * COUT * sizeof(float) + 256;

    if (ws_size >= need_sorted) {
        int*   grid  = (int*)d_ws;
        int*   sorig = (int*)((char*)d_ws + off_sorig);
        int*   skeys = (int*)((char*)d_ws + off_skeys);
        uint4* featb = (uint4*)((char*)d_ws + off_featbf);
        int*   bcnt  = (int*)((char*)d_ws + off_bcnt);
        int*   bbase = (int*)((char*)d_ws + off_bbase);
        uint4* wfrag = (uint4*)((char*)d_ws + off_wfrag);
        float* stats = (float*)((char*)d_ws + off_stats);
        float* scsh  = (float*)((char*)d_ws + off_scsh);

        hipMemsetAsync(d_ws, 0xFF, table_b, stream);
        hipMemsetAsync(featb + N, 0, 16, stream);              // zero row
        hipMemsetAsync(stats, 0, (size_t)64 * 64 * 4, stream);
        prep_wfrag<<<4, threads, 0, stream>>>(W, wfrag);
        build_dense<<<blocksN, threads, 0, stream>>>(coords, N, grid);
        count_kernel<<<NBLK_C, threads, 0, stream>>>(grid, bcnt);
        scan_kernel<<<1, threads, 0, stream>>>(bcnt, bbase);
        fill_kernel<<<NBLK_C, threads, 0, stream>>>(grid, feat, bbase, sorig, skeys, featb);
        int cblocks = (N + 63) / 64;
        conv_mfma<<<cblocks, threads, 0, stream>>>(featb, skeys, sorig, wfrag, grid, N, out, stats);
        finalize_sliced<<<1, 64, 0, stream>>>(stats, gamma, beta, 1.0f / (float)N, scsh);
        norm_kernel<<<2048, threads, 0, stream>>>(out, total_vec, scsh);
        return;
    }

    // ---------- fallback (R2 behavior) ----------
    size_t dense_bytes = table_b;
    bool dense = (ws_size >= dense_bytes + 512);
    size_t table_bytes;
    uint32_t bits = 22, mask = 0;
    if (dense) {
        table_bytes = dense_bytes;
    } else {
        while (bits > 20 && ((size_t)8 << bits) + 512 > ws_size) bits--;
        table_bytes = (size_t)8 << bits;
        mask = (1u << bits) - 1u;
    }
    float* stats = (float*)d_ws;
    float* scsh  = stats + 2 * COUT;

    hipMemsetAsync(d_ws, 0xFF, table_bytes, stream);
    if (dense) {
        build_dense<<<blocksN, threads, 0, stream>>>(coords, N, (int*)d_ws);
        conv_kernel<true><<<blocksN, threads, 0, stream>>>(feat, coords, W, d_ws, 0, 0, N, out);
    } else {
        build_hash<<<blocksN, threads, 0, stream>>>(coords, N, (unsigned long long*)d_ws, bits, mask);
        conv_kernel<false><<<blocksN, threads, 0, stream>>>(feat, coords, W, d_ws, bits, mask, N, out);
    }
    hipMemsetAsync(stats, 0, 2 * COUT * sizeof(float), stream);
    stats_kernel<<<1024, threads, 0, stream>>>(out, total_vec, stats);
    finalize_flat<<<1, 64, 0, stream>>>(stats, gamma, beta, 1.0f / (float)N, scsh);
    norm_kernel<<<2048, threads, 0, stream>>>(out, total_vec, scsh);
}

// Round 6
// 238.894 us; speedup vs baseline: 2.4064x; 1.0206x over previous
//
#include <hip/hip_runtime.h>
#include <stdint.h>

#define GRIDX 200
#define NCELL (GRIDX * GRIDX * GRIDX)          // 8,000,000
#define CIN 6
#define COUT 32
#define NOFF 27
#define BN_EPS 1e-5f
#define CPB 4096                                // cells per compaction block
#define NBLK_C ((NCELL + CPB - 1) / CPB)        // 1954
#define PER 8                                   // scan items/thread

typedef __attribute__((ext_vector_type(8))) short short8;
typedef __attribute__((ext_vector_type(4))) float f32x4;

// ---------------- helpers ----------------

__device__ __forceinline__ int xcd_swizzle(int b, int nwg) {
    int q = nwg >> 3, r = nwg & 7;
    int xcd = b & 7, idx = b >> 3;
    int base = (xcd < r) ? xcd * (q + 1) : r * (q + 1) + (xcd - r) * q;
    return base + idx;
}

__device__ __forceinline__ unsigned short f2bf(float f) {
    uint32_t u = __float_as_uint(f);
    return (unsigned short)((u + 0x7FFFu + ((u >> 16) & 1u)) >> 16);   // RNE
}

// ---------------- table build ----------------

__global__ void build_dense(const int* __restrict__ coords, int N, int* __restrict__ grid) {
    int i = blockIdx.x * blockDim.x + threadIdx.x;
    if (i >= N) return;
    int x = coords[3 * i], y = coords[3 * i + 1], z = coords[3 * i + 2];
    grid[(x * GRIDX + y) * GRIDX + z] = i;
}

__global__ void build_hash(const int* __restrict__ coords, int N,
                           unsigned long long* __restrict__ table,
                           uint32_t bits, uint32_t mask) {
    int i = blockIdx.x * blockDim.x + threadIdx.x;
    if (i >= N) return;
    int x = coords[3 * i], y = coords[3 * i + 1], z = coords[3 * i + 2];
    uint32_t key = (uint32_t)((x * GRIDX + y) * GRIDX + z);
    unsigned long long packed = ((unsigned long long)key << 32) | (uint32_t)i;
    uint32_t h = (key * 2654435761u) >> (32u - bits);
    for (uint32_t p = 0; p <= mask; p++) {
        unsigned long long prev = atomicCAS(&table[h], ~0ull, packed);
        if (prev == ~0ull) return;
        h = (h + 1) & mask;
    }
}

__device__ __forceinline__ int lookup_hash(const unsigned long long* __restrict__ t,
                                           uint32_t key, uint32_t bits, uint32_t mask) {
    uint32_t h = (key * 2654435761u) >> (32u - bits);
    for (uint32_t p = 0; p <= mask; p++) {
        unsigned long long e = t[h];
        if (e == ~0ull) return -1;
        if ((uint32_t)(e >> 32) == key) return (int)(uint32_t)e;
        h = (h + 1) & mask;
    }
    return -1;
}

// ---------------- compaction (sorted path) ----------------

__global__ __launch_bounds__(256)
void count_kernel(const int* __restrict__ grid, int* __restrict__ blockcounts) {
    __shared__ int tot[256];
    int b = blockIdx.x, t = threadIdx.x;
    int cell0 = b * CPB + t * 16;
    int cnt = 0;
#pragma unroll
    for (int j = 0; j < 16; j++) {
        int c = cell0 + j;
        if (c < NCELL && grid[c] >= 0) cnt++;
    }
    tot[t] = cnt;
    __syncthreads();
    if (t < 128) tot[t] += tot[t + 128];
    __syncthreads();
    if (t < 64) {
        int v = tot[t] + tot[t + 64];
#pragma unroll
        for (int d = 32; d > 0; d >>= 1) v += __shfl_down(v, d);
        if (t == 0) blockcounts[b] = v;
    }
}

__global__ __launch_bounds__(256)
void scan_kernel(const int* __restrict__ cnt, int* __restrict__ base) {
    __shared__ int tot[256];
    int t = threadIdx.x;
    int local[PER];
    int s = 0;
#pragma unroll
    for (int j = 0; j < PER; j++) {
        int idx = t * PER + j;
        int v = (idx < NBLK_C) ? cnt[idx] : 0;
        local[j] = s;
        s += v;
    }
    tot[t] = s;
    __syncthreads();
    for (int d = 1; d < 256; d <<= 1) {
        int v = (t >= d) ? tot[t - d] : 0;
        __syncthreads();
        tot[t] += v;
        __syncthreads();
    }
    int tbase = (t == 0) ? 0 : tot[t - 1];
#pragma unroll
    for (int j = 0; j < PER; j++) {
        int idx = t * PER + j;
        if (idx < NBLK_C) base[idx] = tbase + local[j];
    }
}

// fill: compact grid -> ranks; emit bf16x8 feature rows (16B, ci=6,7 zero)
__global__ __launch_bounds__(256)
void fill_kernel(int* __restrict__ grid, const float* __restrict__ feat,
                 const int* __restrict__ blockbase,
                 int* __restrict__ sorted_orig, int* __restrict__ skeys,
                 uint4* __restrict__ feat_bf) {
    __shared__ int tot[256];
    int b = blockIdx.x, t = threadIdx.x;
    int cell0 = b * CPB + t * 16;
    int myorig[16];
    int cnt = 0;
#pragma unroll
    for (int j = 0; j < 16; j++) {
        int c = cell0 + j;
        int v = (c < NCELL) ? grid[c] : -1;
        myorig[j] = v;
        cnt += (v >= 0) ? 1 : 0;
    }
    tot[t] = cnt;
    __syncthreads();
    for (int d = 1; d < 256; d <<= 1) {
        int v = (t >= d) ? tot[t - d] : 0;
        __syncthreads();
        tot[t] += v;
        __syncthreads();
    }
    int jb = blockbase[b] + ((t == 0) ? 0 : tot[t - 1]);
#pragma unroll
    for (int j = 0; j < 16; j++) {
        int v = myorig[j];
        if (v >= 0) {
            int cell = cell0 + j;
            grid[cell] = jb;                       // dense table now holds RANK
            sorted_orig[jb] = v;
            skeys[jb] = cell;
            const float* fr = feat + (size_t)v * CIN;
            float2 a = *(const float2*)fr;
            float2 bb = *(const float2*)(fr + 2);
            float2 cc = *(const float2*)(fr + 4);
            uint4 u;
            u.x = (uint32_t)f2bf(a.x) | ((uint32_t)f2bf(a.y) << 16);
            u.y = (uint32_t)f2bf(bb.x) | ((uint32_t)f2bf(bb.y) << 16);
            u.z = (uint32_t)f2bf(cc.x) | ((uint32_t)f2bf(cc.y) << 16);
            u.w = 0u;
            feat_bf[jb] = u;
            jb++;
        }
    }
}

// ---------------- W fragment prep (once) ----------------
// K-packing: k = koff*8 + ci (ci<6 real, ci=6,7 zero; koff>=27 zero).
// B-fragment (16x16x32 bf16): lane l holds B[k = ks*32+(l>>4)*8+b][col = nt*16+(l&15)]
// Layout: wfrag[(ks*2+nt)*64 + l] = 8 bf16.

__global__ void prep_wfrag(const float* __restrict__ W, uint4* __restrict__ wfrag) {
    int idx = blockIdx.x * blockDim.x + threadIdx.x;
    if (idx >= 7 * 2 * 64) return;
    int l = idx & 63;
    int nt = (idx >> 6) & 1;
    int ks = idx >> 7;
    int koff = ks * 4 + (l >> 4);
    int col = nt * 16 + (l & 15);
    unsigned short v[8];
#pragma unroll
    for (int ci = 0; ci < 8; ci++) {
        float f = 0.f;
        if (ci < CIN && koff < NOFF) f = W[(koff * CIN + ci) * COUT + col];
        v[ci] = f2bf(f);
    }
    uint4 u;
    u.x = (uint32_t)v[0] | ((uint32_t)v[1] << 16);
    u.y = (uint32_t)v[2] | ((uint32_t)v[3] << 16);
    u.z = (uint32_t)v[4] | ((uint32_t)v[5] << 16);
    u.w = (uint32_t)v[6] | ((uint32_t)v[7] << 16);
    wfrag[idx] = u;
}

// ---------------- conv: register-direct gather -> MFMA, fused stats ----------------
// Lane l of wave w computes sites bs + w*16 + (l&15); per ks it gathers the
// A-fragment row (site, koff = ks*4 + (l>>4)) straight into registers —
// equivalence with the R5 LDS mapping verified algebraically (same (site,koff)
// per (w,l,ks)). No LDS staging, no barrier in the main loop.

__global__ __launch_bounds__(256, 4)
void conv_mfma(const uint4* __restrict__ feat_bf,      // N+1 rows (row N = zeros)
               const int* __restrict__ skeys,
               const int* __restrict__ sorig,
               const uint4* __restrict__ wfrag,
               const int* __restrict__ grid_tab, int N,
               float* __restrict__ out,
               float* __restrict__ stats_g) {
    __shared__ __align__(16) float Clds[64 * 36];    // 9216 B
    __shared__ float bstat[64];

    int tid = threadIdx.x;
    int w = tid >> 6, l = tid & 63;

    if (tid < 64) bstat[tid] = 0.f;
    __syncthreads();

    // B fragments in registers (coalesced, L2-resident after first blocks)
    const short8* wf8 = (const short8*)wfrag;
    short8 bf0[7], bf1[7];
#pragma unroll
    for (int ks = 0; ks < 7; ks++) {
        bf0[ks] = wf8[(ks * 2 + 0) * 64 + l];
        bf1[ks] = wf8[(ks * 2 + 1) * 64 + l];
    }

    int b = xcd_swizzle(blockIdx.x, gridDim.x);
    int bs = b * 64;
    int site = bs + w * 16 + (l & 15);   // the site this lane's A-rows belong to
    bool sv = (site < N);
    int key = sv ? skeys[site] : 0;
    int x = key / (GRIDX * GRIDX);
    int rem = key % (GRIDX * GRIDX);
    int y = rem / GRIDX;
    int z = rem % GRIDX;
    int kb = l >> 4;

    f32x4 acc0 = {0.f, 0.f, 0.f, 0.f};
    f32x4 acc1 = {0.f, 0.f, 0.f, 0.f};
    const short8* fb8 = (const short8*)feat_bf;

#pragma unroll
    for (int ks = 0; ks < 7; ks++) {
        int koff = ks * 4 + kb;          // 0..27 (27 = zero-pad)
        int t9 = koff / 9;
        int r9 = koff - t9 * 9;
        int t3 = r9 / 3;
        int dx = t9 - 1, dy = t3 - 1, dz = r9 - t3 * 3 - 1;
        int nx = x + dx, ny = y + dy, nz = z + dz;
        bool ok = sv && (koff < NOFF) &&
                  ((unsigned)nx < GRIDX) && ((unsigned)ny < GRIDX) && ((unsigned)nz < GRIDX);
        int nkey = key + dx * (GRIDX * GRIDX) + dy * GRIDX + dz;
        nkey = min(max(nkey, 0), NCELL - 1);
        int pos = grid_tab[nkey];        // table always valid
        pos = (ok && pos >= 0) ? pos : N;  // miss -> zero row (branch-free)
        short8 a = fb8[pos];
        acc0 = __builtin_amdgcn_mfma_f32_16x16x32_bf16(a, bf0[ks], acc0, 0, 0, 0);
        acc1 = __builtin_amdgcn_mfma_f32_16x16x32_bf16(a, bf1[ks], acc1, 0, 0, 0);
    }

    int col = l & 15;
    int rg = l >> 4;

    // C transpose staging (each thread writes its own slots; sync below)
#pragma unroll
    for (int r = 0; r < 4; r++) {
        int s = w * 16 + rg * 4 + r;     // C/D map: col=lane&15, row=(lane>>4)*4+r
        Clds[s * 36 + col] = acc0[r];
        Clds[s * 36 + col + 16] = acc1[r];
    }

    // fused BN stats (pre-norm); invalid sites contribute exact zeros
    float s0 = acc0[0] + acc0[1] + acc0[2] + acc0[3];
    float q0 = acc0[0]*acc0[0] + acc0[1]*acc0[1] + acc0[2]*acc0[2] + acc0[3]*acc0[3];
    float s1 = acc1[0] + acc1[1] + acc1[2] + acc1[3];
    float q1 = acc1[0]*acc1[0] + acc1[1]*acc1[1] + acc1[2]*acc1[2] + acc1[3]*acc1[3];
    s0 += __shfl_xor(s0, 16); s0 += __shfl_xor(s0, 32);
    q0 += __shfl_xor(q0, 16); q0 += __shfl_xor(q0, 32);
    s1 += __shfl_xor(s1, 16); s1 += __shfl_xor(s1, 32);
    q1 += __shfl_xor(q1, 16); q1 += __shfl_xor(q1, 32);
    if (l < 16) {
        atomicAdd(&bstat[col], s0);
        atomicAdd(&bstat[16 + col], s1);
        atomicAdd(&bstat[32 + col], q0);
        atomicAdd(&bstat[48 + col], q1);
    }
    __syncthreads();                     // Clds writes + bstat complete

    if (tid < 64) {
        int slice = blockIdx.x & 63;
        atomicAdd(&stats_g[slice * 64 + tid], bstat[tid]);
    }

    int st = tid >> 2;                   // site-local 0..63
    int q = (tid & 3) * 2;               // chunk pair
    int sr = bs + st;
    if (sr < N) {
        float4* gp = (float4*)(out + (size_t)sorig[sr] * COUT + q * 4);
        gp[0] = *(const float4*)&Clds[st * 36 + q * 4];
        gp[1] = *(const float4*)&Clds[st * 36 + q * 4 + 4];
    }
}

// ---------------- BN finalize / norm ----------------

__global__ void finalize_sliced(const float* __restrict__ stats_g,
                                const float* __restrict__ gamma,
                                const float* __restrict__ beta,
                                float invN, float* __restrict__ scsh) {
    int c = threadIdx.x;
    if (c < COUT) {
        float s = 0.f, q = 0.f;
        for (int sl = 0; sl < 64; sl++) {
            s += stats_g[sl * 64 + c];
            q += stats_g[sl * 64 + 32 + c];
        }
        float mean = s * invN;
        float var = q * invN - mean * mean;
        float sc = gamma[c] * rsqrtf(var + BN_EPS);
        scsh[c] = sc;
        scsh[COUT + c] = beta[c] - mean * sc;
    }
}

__global__ __launch_bounds__(256)
void norm_kernel(float* __restrict__ out, long total_vec,
                 const float* __restrict__ scaleshift) {
    __shared__ float sc[COUT], sh[COUT];
    for (int t = threadIdx.x; t < COUT; t += blockDim.x) {
        sc[t] = scaleshift[t];
        sh[t] = scaleshift[COUT + t];
    }
    __syncthreads();
    long stride = (long)gridDim.x * blockDim.x;
    float4* p = (float4*)out;
    for (long v = (long)blockIdx.x * blockDim.x + threadIdx.x; v < total_vec; v += stride) {
        int cbase = (int)(v & 7) * 4;
        float4 u = p[v];
        u.x = fmaxf(u.x * sc[cbase + 0] + sh[cbase + 0], 0.f);
        u.y = fmaxf(u.y * sc[cbase + 1] + sh[cbase + 1], 0.f);
        u.z = fmaxf(u.z * sc[cbase + 2] + sh[cbase + 2], 0.f);
        u.w = fmaxf(u.w * sc[cbase + 3] + sh[cbase + 3], 0.f);
        p[v] = u;
    }
}

// ---------------- fallback path kernels (R2) ----------------

template <bool DENSE>
__global__ __launch_bounds__(256)
void conv_kernel(const float* __restrict__ feat,
                 const int* __restrict__ coords,
                 const float* __restrict__ W,
                 const void* __restrict__ table,
                 uint32_t bits, uint32_t mask, int N,
                 float* __restrict__ out) {
    __shared__ __align__(16) float wlds[NOFF * CIN * COUT];
    for (int t = threadIdx.x; t < NOFF * CIN * COUT; t += blockDim.x)
        wlds[t] = W[t];
    __syncthreads();

    int i = blockIdx.x * blockDim.x + threadIdx.x;
    if (i >= N) return;
    int x = coords[3 * i], y = coords[3 * i + 1], z = coords[3 * i + 2];

    float acc[COUT];
#pragma unroll
    for (int c = 0; c < COUT; c++) acc[c] = 0.f;

#pragma unroll 1
    for (int k = 0; k < NOFF; k++) {
        int dx = k / 9 - 1, dy = (k / 3) % 3 - 1, dz = k % 3 - 1;
        int nx = x + dx, ny = y + dy, nz = z + dz;
        int idx = -1;
        if ((unsigned)nx < GRIDX && (unsigned)ny < GRIDX && (unsigned)nz < GRIDX) {
            uint32_t key = (uint32_t)((nx * GRIDX + ny) * GRIDX + nz);
            if (DENSE) idx = ((const int*)table)[key];
            else       idx = lookup_hash((const unsigned long long*)table, key, bits, mask);
        }
        if (idx >= 0) {
            const float* fr = feat + (size_t)idx * CIN;
            float2 a = *(const float2*)(fr);
            float2 b = *(const float2*)(fr + 2);
            float2 c2 = *(const float2*)(fr + 4);
            float f[CIN] = {a.x, a.y, b.x, b.y, c2.x, c2.y};
            const float* wk = &wlds[k * CIN * COUT];
#pragma unroll
            for (int ci = 0; ci < CIN; ci++) {
                const float4* w4 = (const float4*)(wk + ci * COUT);
                float fv = f[ci];
#pragma unroll
                for (int q = 0; q < COUT / 4; q++) {
                    float4 wv = w4[q];
                    acc[4 * q + 0] += fv * wv.x;
                    acc[4 * q + 1] += fv * wv.y;
                    acc[4 * q + 2] += fv * wv.z;
                    acc[4 * q + 3] += fv * wv.w;
                }
            }
        }
    }

    float4* op = (float4*)(out + (size_t)i * COUT);
#pragma unroll
    for (int q = 0; q < COUT / 4; q++) {
        float4 v;
        v.x = acc[4 * q + 0];
        v.y = acc[4 * q + 1];
        v.z = acc[4 * q + 2];
        v.w = acc[4 * q + 3];
        op[q] = v;
    }
}

__global__ __launch_bounds__(256)
void stats_kernel(const float* __restrict__ out, long total_vec,
                  float* __restrict__ stats) {
    __shared__ float lsum[COUT], lsq[COUT];
    for (int t = threadIdx.x; t < COUT; t += blockDim.x) { lsum[t] = 0.f; lsq[t] = 0.f; }
    __syncthreads();

    long stride = (long)gridDim.x * blockDim.x;
    long v0 = (long)blockIdx.x * blockDim.x + threadIdx.x;
    int cbase = (int)(v0 & 7) * 4;
    float s[4] = {0, 0, 0, 0}, q[4] = {0, 0, 0, 0};
    const float4* p = (const float4*)out;
    for (long v = v0; v < total_vec; v += stride) {
        float4 u = p[v];
        s[0] += u.x; q[0] += u.x * u.x;
        s[1] += u.y; q[1] += u.y * u.y;
        s[2] += u.z; q[2] += u.z * u.z;
        s[3] += u.w; q[3] += u.w * u.w;
    }
#pragma unroll
    for (int j = 0; j < 4; j++) {
        atomicAdd(&lsum[cbase + j], s[j]);
        atomicAdd(&lsq[cbase + j], q[j]);
    }
    __syncthreads();
    for (int t = threadIdx.x; t < COUT; t += blockDim.x) {
        atomicAdd(&stats[t], lsum[t]);
        atomicAdd(&stats[COUT + t], lsq[t]);
    }
}

__global__ void finalize_flat(const float* __restrict__ stats,
                              const float* __restrict__ gamma,
                              const float* __restrict__ beta,
                              float invN, float* __restrict__ scaleshift) {
    int c = threadIdx.x;
    if (c < COUT) {
        float mean = stats[c] * invN;
        float var = stats[COUT + c] * invN - mean * mean;
        float sc = gamma[c] * rsqrtf(var + BN_EPS);
        scaleshift[c] = sc;
        scaleshift[COUT + c] = beta[c] - mean * sc;
    }
}

// ---------------- launch ----------------

extern "C" void kernel_launch(void* const* d_in, const int* in_sizes, int n_in,
                              void* d_out, int out_size, void* d_ws, size_t ws_size,
                              hipStream_t stream) {
    const float* feat   = (const float*)d_in[0];
    const int*   coords = (const int*)d_in[1];
    const float* W      = (const float*)d_in[2];
    const float* gamma  = (const float*)d_in[3];
    const float* beta   = (const float*)d_in[4];
    float* out = (float*)d_out;

    int N = in_sizes[0] / CIN;
    const int threads = 256;
    int blocksN = (N + threads - 1) / threads;
    long total_vec = (long)N * COUT / 4;

    size_t a256 = 255;
    size_t table_b    = (size_t)NCELL * 4;                     // 32 MB
    size_t off_sorig  = (table_b + a256) & ~a256;
    size_t off_skeys  = (off_sorig + (size_t)N * 4 + a256) & ~a256;
    size_t off_featbf = (off_skeys + (size_t)N * 4 + a256) & ~a256;
    size_t off_bcnt   = (off_featbf + (size_t)(N + 1) * 16 + a256) & ~a256;
    size_t off_bbase  = (off_bcnt + (size_t)NBLK_C * 4 + a256) & ~a256;
    size_t off_wfrag  = (off_bbase + (size_t)NBLK_C * 4 + a256) & ~a256;
    size_t off_stats  = (off_wfrag + (size_t)(7 * 2 * 64) * 16 + a256) & ~a256;
    size_t off_scsh   = off_stats + (size_t)64 * 64 * 4;
    size_t need_sorted = off_scsh + 2 * COUT * sizeof(float) + 256;

    if (ws_size >= need_sorted) {
        int*   grid  = (int*)d_ws;
        int*   sorig = (int*)((char*)d_ws + off_sorig);
        int*   skeys = (int*)((char*)d_ws + off_skeys);
        uint4* featb = (uint4*)((char*)d_ws + off_featbf);
        int*   bcnt  = (int*)((char*)d_ws + off_bcnt);
        int*   bbase = (int*)((char*)d_ws + off_bbase);
        uint4* wfrag = (uint4*)((char*)d_ws + off_wfrag);
        float* stats = (float*)((char*)d_ws + off_stats);
        float* scsh  = (float*)((char*)d_ws + off_scsh);

        hipMemsetAsync(d_ws, 0xFF, table_b, stream);
        hipMemsetAsync(featb + N, 0, 16, stream);              // zero row
        hipMemsetAsync(stats, 0, (size_t)64 * 64 * 4, stream);
        prep_wfrag<<<4, threads, 0, stream>>>(W, wfrag);
        build_dense<<<blocksN, threads, 0, stream>>>(coords, N, grid);
        count_kernel<<<NBLK_C, threads, 0, stream>>>(grid, bcnt);
        scan_kernel<<<1, threads, 0, stream>>>(bcnt, bbase);
        fill_kernel<<<NBLK_C, threads, 0, stream>>>(grid, feat, bbase, sorig, skeys, featb);
        int cblocks = (N + 63) / 64;
        conv_mfma<<<cblocks, threads, 0, stream>>>(featb, skeys, sorig, wfrag, grid, N, out, stats);
        finalize_sliced<<<1, 64, 0, stream>>>(stats, gamma, beta, 1.0f / (float)N, scsh);
        norm_kernel<<<2048, threads, 0, stream>>>(out, total_vec, scsh);
        return;
    }

    // ---------- fallback (R2 behavior) ----------
    size_t dense_bytes = table_b;
    bool dense = (ws_size >= dense_bytes + 512);
    size_t table_bytes;
    uint32_t bits = 22, mask = 0;
    if (dense) {
        table_bytes = dense_bytes;
    } else {
        while (bits > 20 && ((size_t)8 << bits) + 512 > ws_size) bits--;
        table_bytes = (size_t)8 << bits;
        mask = (1u << bits) - 1u;
    }
    float* stats = (float*)d_ws;
    float* scsh  = stats + 2 * COUT;

    hipMemsetAsync(d_ws, 0xFF, table_bytes, stream);
    if (dense) {
        build_dense<<<blocksN, threads, 0, stream>>>(coords, N, (int*)d_ws);
        conv_kernel<true><<<blocksN, threads, 0, stream>>>(feat, coords, W, d_ws, 0, 0, N, out);
    } else {
        build_hash<<<blocksN, threads, 0, stream>>>(coords, N, (unsigned long long*)d_ws, bits, mask);
        conv_kernel<false><<<blocksN, threads, 0, stream>>>(feat, coords, W, d_ws, bits, mask, N, out);
    }
    hipMemsetAsync(stats, 0, 2 * COUT * sizeof(float), stream);
    stats_kernel<<<1024, threads, 0, stream>>>(out, total_vec, stats);
    finalize_flat<<<1, 64, 0, stream>>>(stats, gamma, beta, 1.0f / (float)N, scsh);
    norm_kernel<<<2048, threads, 0, stream>>>(out, total_vec, scsh);
}

// Round 8
// 229.103 us; speedup vs baseline: 2.5092x; 1.0427x over previous
//
#include <hip/hip_runtime.h>
#include <stdint.h>

#define GRIDX 200
#define NCELL (GRIDX * GRIDX * GRIDX)          // 8,000,000
#define NW32 ((NCELL + 31) / 32)               // 250,000 32-bit words
#define CIN 6
#define COUT 32
#define NOFF 27
#define BN_EPS 1e-5f
#define WPB32 1024                              // words per count/base block
#define NBLK32 ((NW32 + WPB32 - 1) / WPB32)     // 245 (<=256 for single-block scan)

typedef __attribute__((ext_vector_type(8))) short short8;
typedef __attribute__((ext_vector_type(4))) float f32x4;

// ---------------- helpers ----------------

__device__ __forceinline__ int xcd_swizzle(int b, int nwg) {
    int q = nwg >> 3, r = nwg & 7;
    int xcd = b & 7, idx = b >> 3;
    int base = (xcd < r) ? xcd * (q + 1) : r * (q + 1) + (xcd - r) * q;
    return base + idx;
}

__device__ __forceinline__ unsigned short f2bf(float f) {
    uint32_t u = __float_as_uint(f);
    return (unsigned short)((u + 0x7FFFu + ((u >> 16) & 1u)) >> 16);   // RNE
}

// ---------------- 32-bit bitmap rank structure ----------------

__global__ void build_bitmap32(const int* __restrict__ coords, int N,
                               uint32_t* __restrict__ words) {
    int i = blockIdx.x * blockDim.x + threadIdx.x;
    if (i >= N) return;
    int x = coords[3 * i], y = coords[3 * i + 1], z = coords[3 * i + 2];
    int key = (x * GRIDX + y) * GRIDX + z;
    atomicOr(&words[key >> 5], 1u << (key & 31));
}

__global__ __launch_bounds__(256)
void bitmap_count32(const uint32_t* __restrict__ words, int* __restrict__ bcnt) {
    __shared__ int tot[256];
    int b = blockIdx.x, t = threadIdx.x;
    int w0 = b * WPB32 + t * 4;
    int s = 0;
#pragma unroll
    for (int j = 0; j < 4; j++) {
        int w = w0 + j;
        if (w < NW32) s += __popc(words[w]);
    }
    tot[t] = s;
    __syncthreads();
    if (t < 128) tot[t] += tot[t + 128];
    __syncthreads();
    if (t < 64) {
        int v = tot[t] + tot[t + 64];
#pragma unroll
        for (int d = 32; d > 0; d >>= 1) v += __shfl_down(v, d);
        if (t == 0) bcnt[b] = v;
    }
}

// exclusive scan of n<=256 values, one block of 256 threads
__global__ void scan_small(const int* __restrict__ cnt, int* __restrict__ base, int n) {
    __shared__ int tot[256];
    int t = threadIdx.x;
    int v = (t < n) ? cnt[t] : 0;
    tot[t] = v;
    __syncthreads();
    for (int d = 1; d < 256; d <<= 1) {
        int u = (t >= d) ? tot[t - d] : 0;
        __syncthreads();
        tot[t] += u;
        __syncthreads();
    }
    if (t < n) base[t] = tot[t] - v;     // exclusive
}

__global__ __launch_bounds__(256)
void base_fill32(const uint32_t* __restrict__ words, const int* __restrict__ bbase,
                 uint32_t* __restrict__ bases) {
    __shared__ int tot[256];
    int b = blockIdx.x, t = threadIdx.x;
    int w0 = b * WPB32 + t * 4;
    int p[4];
    int s = 0;
#pragma unroll
    for (int j = 0; j < 4; j++) {
        int w = w0 + j;
        p[j] = (w < NW32) ? __popc(words[w]) : 0;
        s += p[j];
    }
    tot[t] = s;
    __syncthreads();
    for (int d = 1; d < 256; d <<= 1) {
        int u = (t >= d) ? tot[t - d] : 0;
        __syncthreads();
        tot[t] += u;
        __syncthreads();
    }
    int run = bbase[b] + tot[t] - s;     // exclusive global rank of first word
#pragma unroll
    for (int j = 0; j < 4; j++) {
        int w = w0 + j;
        if (w < NW32) bases[w] = (uint32_t)run;
        run += p[j];
    }
}

// ---------------- rank scatter: original order -> sorted order ----------------

__global__ __launch_bounds__(256)
void rank_scatter32(const int* __restrict__ coords, const float* __restrict__ feat, int N,
                    const uint32_t* __restrict__ words, const uint32_t* __restrict__ bases,
                    int* __restrict__ sorig, int* __restrict__ skeys,
                    uint4* __restrict__ feat_bf) {
    int i = blockIdx.x * blockDim.x + threadIdx.x;
    if (i >= N) return;
    int x = coords[3 * i], y = coords[3 * i + 1], z = coords[3 * i + 2];
    int key = (x * GRIDX + y) * GRIDX + z;
    int wi = key >> 5;
    int bit = key & 31;
    uint32_t wd = words[wi];
    int r = (int)(bases[wi] + (uint32_t)__popc(wd & ((1u << bit) - 1u)));
    sorig[r] = i;
    skeys[r] = key;
    const float* fr = feat + (size_t)i * CIN;
    float2 a = *(const float2*)fr;
    float2 bb = *(const float2*)(fr + 2);
    float2 cc = *(const float2*)(fr + 4);
    uint4 u;
    u.x = (uint32_t)f2bf(a.x) | ((uint32_t)f2bf(a.y) << 16);
    u.y = (uint32_t)f2bf(bb.x) | ((uint32_t)f2bf(bb.y) << 16);
    u.z = (uint32_t)f2bf(cc.x) | ((uint32_t)f2bf(cc.y) << 16);
    u.w = 0u;
    feat_bf[r] = u;
}

// ---------------- W fragment prep (once) ----------------
// K-packing: k = koff*8 + ci (ci<6 real, ci=6,7 zero; koff>=27 zero).
// B-fragment (16x16x32 bf16): lane l holds B[k = ks*32+(l>>4)*8+b][col = nt*16+(l&15)]

__global__ void prep_wfrag(const float* __restrict__ W, uint4* __restrict__ wfrag) {
    int idx = blockIdx.x * blockDim.x + threadIdx.x;
    if (idx >= 7 * 2 * 64) return;
    int l = idx & 63;
    int nt = (idx >> 6) & 1;
    int ks = idx >> 7;
    int koff = ks * 4 + (l >> 4);
    int col = nt * 16 + (l & 15);
    unsigned short v[8];
#pragma unroll
    for (int ci = 0; ci < 8; ci++) {
        float f = 0.f;
        if (ci < CIN && koff < NOFF) f = W[(koff * CIN + ci) * COUT + col];
        v[ci] = f2bf(f);
    }
    uint4 u;
    u.x = (uint32_t)v[0] | ((uint32_t)v[1] << 16);
    u.y = (uint32_t)v[2] | ((uint32_t)v[3] << 16);
    u.z = (uint32_t)v[4] | ((uint32_t)v[5] << 16);
    u.w = (uint32_t)v[6] | ((uint32_t)v[7] << 16);
    wfrag[idx] = u;
}

// ---------------- conv: register-direct gather (32-bit bitmap rank) -> MFMA, fused stats ----------------

__global__ __launch_bounds__(256, 4)
void conv_mfma(const uint4* __restrict__ feat_bf,      // N+1 rows (row N = zeros)
               const int* __restrict__ skeys,
               const int* __restrict__ sorig,
               const uint4* __restrict__ wfrag,
               const uint32_t* __restrict__ words,
               const uint32_t* __restrict__ bases, int N,
               float* __restrict__ out,
               float* __restrict__ stats_g) {
    __shared__ __align__(16) float Clds[64 * 36];    // 9216 B
    __shared__ float bstat[64];

    int tid = threadIdx.x;
    int w = tid >> 6, l = tid & 63;

    if (tid < 64) bstat[tid] = 0.f;
    __syncthreads();

    const short8* wf8 = (const short8*)wfrag;
    short8 bf0[7], bf1[7];
#pragma unroll
    for (int ks = 0; ks < 7; ks++) {
        bf0[ks] = wf8[(ks * 2 + 0) * 64 + l];
        bf1[ks] = wf8[(ks * 2 + 1) * 64 + l];
    }

    int b = xcd_swizzle(blockIdx.x, gridDim.x);
    int bs = b * 64;
    int site = bs + w * 16 + (l & 15);   // the site this lane's A-rows belong to
    bool sv = (site < N);
    int key = sv ? skeys[site] : 0;
    int x = key / (GRIDX * GRIDX);
    int rem = key % (GRIDX * GRIDX);
    int y = rem / GRIDX;
    int z = rem % GRIDX;
    int kb = l >> 4;

    f32x4 acc0 = {0.f, 0.f, 0.f, 0.f};
    f32x4 acc1 = {0.f, 0.f, 0.f, 0.f};
    const short8* fb8 = (const short8*)feat_bf;

#pragma unroll
    for (int ks = 0; ks < 7; ks++) {
        int koff = ks * 4 + kb;          // 0..27 (27 = zero-pad)
        int t9 = koff / 9;
        int r9 = koff - t9 * 9;
        int t3 = r9 / 3;
        int dx = t9 - 1, dy = t3 - 1, dz = r9 - t3 * 3 - 1;
        int nx = x + dx, ny = y + dy, nz = z + dz;
        bool ok = sv && (koff < NOFF) &&
                  ((unsigned)nx < GRIDX) && ((unsigned)ny < GRIDX) && ((unsigned)nz < GRIDX);
        int nkey = key + dx * (GRIDX * GRIDX) + dy * GRIDX + dz;
        nkey = min(max(nkey, 0), NCELL - 1);
        int wi = nkey >> 5;
        int bit = nkey & 31;
        uint32_t wd = words[wi];         // plain 4B loads, 2MB L2-resident
        uint32_t bb = bases[wi];
        bool hit = ok && ((wd >> bit) & 1u);
        int pos = hit ? (int)(bb + (uint32_t)__popc(wd & ((1u << bit) - 1u))) : N;
        short8 a = fb8[pos];
        acc0 = __builtin_amdgcn_mfma_f32_16x16x32_bf16(a, bf0[ks], acc0, 0, 0, 0);
        acc1 = __builtin_amdgcn_mfma_f32_16x16x32_bf16(a, bf1[ks], acc1, 0, 0, 0);
    }

    int col = l & 15;
    int rg = l >> 4;

    // C transpose staging
#pragma unroll
    for (int r = 0; r < 4; r++) {
        int s = w * 16 + rg * 4 + r;     // C/D map: col=lane&15, row=(lane>>4)*4+r
        Clds[s * 36 + col] = acc0[r];
        Clds[s * 36 + col + 16] = acc1[r];
    }

    // fused BN stats (pre-norm); invalid sites contribute exact zeros
    float s0 = acc0[0] + acc0[1] + acc0[2] + acc0[3];
    float q0 = acc0[0]*acc0[0] + acc0[1]*acc0[1] + acc0[2]*acc0[2] + acc0[3]*acc0[3];
    float s1 = acc1[0] + acc1[1] + acc1[2] + acc1[3];
    float q1 = acc1[0]*acc1[0] + acc1[1]*acc1[1] + acc1[2]*acc1[2] + acc1[3]*acc1[3];
    s0 += __shfl_xor(s0, 16); s0 += __shfl_xor(s0, 32);
    q0 += __shfl_xor(q0, 16); q0 += __shfl_xor(q0, 32);
    s1 += __shfl_xor(s1, 16); s1 += __shfl_xor(s1, 32);
    q1 += __shfl_xor(q1, 16); q1 += __shfl_xor(q1, 32);
    if (l < 16) {
        atomicAdd(&bstat[col], s0);
        atomicAdd(&bstat[16 + col], s1);
        atomicAdd(&bstat[32 + col], q0);
        atomicAdd(&bstat[48 + col], q1);
    }
    __syncthreads();                     // Clds writes + bstat complete

    if (tid < 64) {
        int slice = blockIdx.x & 63;
        atomicAdd(&stats_g[slice * 64 + tid], bstat[tid]);
    }

    int st = tid >> 2;                   // site-local 0..63
    int q = (tid & 3) * 2;               // chunk pair
    int sr = bs + st;
    if (sr < N) {
        float4* gp = (float4*)(out + (size_t)sorig[sr] * COUT + q * 4);
        gp[0] = *(const float4*)&Clds[st * 36 + q * 4];
        gp[1] = *(const float4*)&Clds[st * 36 + q * 4 + 4];
    }
}

// ---------------- BN finalize / norm ----------------

__global__ void finalize_sliced(const float* __restrict__ stats_g,
                                const float* __restrict__ gamma,
                                const float* __restrict__ beta,
                                float invN, float* __restrict__ scsh) {
    int c = threadIdx.x;
    if (c < COUT) {
        float s = 0.f, q = 0.f;
        for (int sl = 0; sl < 64; sl++) {
            s += stats_g[sl * 64 + c];
            q += stats_g[sl * 64 + 32 + c];
        }
        float mean = s * invN;
        float var = q * invN - mean * mean;
        float sc = gamma[c] * rsqrtf(var + BN_EPS);
        scsh[c] = sc;
        scsh[COUT + c] = beta[c] - mean * sc;
    }
}

__global__ __launch_bounds__(256)
void norm_kernel(float* __restrict__ out, long total_vec,
                 const float* __restrict__ scaleshift) {
    __shared__ float sc[COUT], sh[COUT];
    for (int t = threadIdx.x; t < COUT; t += blockDim.x) {
        sc[t] = scaleshift[t];
        sh[t] = scaleshift[COUT + t];
    }
    __syncthreads();
    long stride = (long)gridDim.x * blockDim.x;
    float4* p = (float4*)out;
    for (long v = (long)blockIdx.x * blockDim.x + threadIdx.x; v < total_vec; v += stride) {
        int cbase = (int)(v & 7) * 4;
        float4 u = p[v];
        u.x = fmaxf(u.x * sc[cbase + 0] + sh[cbase + 0], 0.f);
        u.y = fmaxf(u.y * sc[cbase + 1] + sh[cbase + 1], 0.f);
        u.z = fmaxf(u.z * sc[cbase + 2] + sh[cbase + 2], 0.f);
        u.w = fmaxf(u.w * sc[cbase + 3] + sh[cbase + 3], 0.f);
        p[v] = u;
    }
}

// ---------------- fallback path kernels (R2) ----------------

__global__ void build_dense(const int* __restrict__ coords, int N, int* __restrict__ grid) {
    int i = blockIdx.x * blockDim.x + threadIdx.x;
    if (i >= N) return;
    int x = coords[3 * i], y = coords[3 * i + 1], z = coords[3 * i + 2];
    grid[(x * GRIDX + y) * GRIDX + z] = i;
}

__global__ void build_hash(const int* __restrict__ coords, int N,
                           unsigned long long* __restrict__ table,
                           uint32_t bits, uint32_t mask) {
    int i = blockIdx.x * blockDim.x + threadIdx.x;
    if (i >= N) return;
    int x = coords[3 * i], y = coords[3 * i + 1], z = coords[3 * i + 2];
    uint32_t key = (uint32_t)((x * GRIDX + y) * GRIDX + z);
    unsigned long long packed = ((unsigned long long)key << 32) | (uint32_t)i;
    uint32_t h = (key * 2654435761u) >> (32u - bits);
    for (uint32_t p = 0; p <= mask; p++) {
        unsigned long long prev = atomicCAS(&table[h], ~0ull, packed);
        if (prev == ~0ull) return;
        h = (h + 1) & mask;
    }
}

__device__ __forceinline__ int lookup_hash(const unsigned long long* __restrict__ t,
                                           uint32_t key, uint32_t bits, uint32_t mask) {
    uint32_t h = (key * 2654435761u) >> (32u - bits);
    for (uint32_t p = 0; p <= mask; p++) {
        unsigned long long e = t[h];
        if (e == ~0ull) return -1;
        if ((uint32_t)(e >> 32) == key) return (int)(uint32_t)e;
        h = (h + 1) & mask;
    }
    return -1;
}

template <bool DENSE>
__global__ __launch_bounds__(256)
void conv_kernel(const float* __restrict__ feat,
                 const int* __restrict__ coords,
                 const float* __restrict__ W,
                 const void* __restrict__ table,
                 uint32_t bits, uint32_t mask, int N,
                 float* __restrict__ out) {
    __shared__ __align__(16) float wlds[NOFF * CIN * COUT];
    for (int t = threadIdx.x; t < NOFF * CIN * COUT; t += blockDim.x)
        wlds[t] = W[t];
    __syncthreads();

    int i = blockIdx.x * blockDim.x + threadIdx.x;
    if (i >= N) return;
    int x = coords[3 * i], y = coords[3 * i + 1], z = coords[3 * i + 2];

    float acc[COUT];
#pragma unroll
    for (int c = 0; c < COUT; c++) acc[c] = 0.f;

#pragma unroll 1
    for (int k = 0; k < NOFF; k++) {
        int dx = k / 9 - 1, dy = (k / 3) % 3 - 1, dz = k % 3 - 1;
        int nx = x + dx, ny = y + dy, nz = z + dz;
        int idx = -1;
        if ((unsigned)nx < GRIDX && (unsigned)ny < GRIDX && (unsigned)nz < GRIDX) {
            uint32_t key = (uint32_t)((nx * GRIDX + ny) * GRIDX + nz);
            if (DENSE) idx = ((const int*)table)[key];
            else       idx = lookup_hash((const unsigned long long*)table, key, bits, mask);
        }
        if (idx >= 0) {
            const float* fr = feat + (size_t)idx * CIN;
            float2 a = *(const float2*)(fr);
            float2 b = *(const float2*)(fr + 2);
            float2 c2 = *(const float2*)(fr + 4);
            float f[CIN] = {a.x, a.y, b.x, b.y, c2.x, c2.y};
            const float* wk = &wlds[k * CIN * COUT];
#pragma unroll
            for (int ci = 0; ci < CIN; ci++) {
                const float4* w4 = (const float4*)(wk + ci * COUT);
                float fv = f[ci];
#pragma unroll
                for (int q = 0; q < COUT / 4; q++) {
                    float4 wv = w4[q];
                    acc[4 * q + 0] += fv * wv.x;
                    acc[4 * q + 1] += fv * wv.y;
                    acc[4 * q + 2] += fv * wv.z;
                    acc[4 * q + 3] += fv * wv.w;
                }
            }
        }
    }

    float4* op = (float4*)(out + (size_t)i * COUT);
#pragma unroll
    for (int q = 0; q < COUT / 4; q++) {
        float4 v;
        v.x = acc[4 * q + 0];
        v.y = acc[4 * q + 1];
        v.z = acc[4 * q + 2];
        v.w = acc[4 * q + 3];
        op[q] = v;
    }
}

__global__ __launch_bounds__(256)
void stats_kernel(const float* __restrict__ out, long total_vec,
                  float* __restrict__ stats) {
    __shared__ float lsum[COUT], lsq[COUT];
    for (int t = threadIdx.x; t < COUT; t += blockDim.x) { lsum[t] = 0.f; lsq[t] = 0.f; }
    __syncthreads();

    long stride = (long)gridDim.x * blockDim.x;
    long v0 = (long)blockIdx.x * blockDim.x + threadIdx.x;
    int cbase = (int)(v0 & 7) * 4;
    float s[4] = {0, 0, 0, 0}, q[4] = {0, 0, 0, 0};
    const float4* p = (const float4*)out;
    for (long v = v0; v < total_vec; v += stride) {
        float4 u = p[v];
        s[0] += u.x; q[0] += u.x * u.x;
        s[1] += u.y; q[1] += u.y * u.y;
        s[2] += u.z; q[2] += u.z * u.z;
        s[3] += u.w; q[3] += u.w * u.w;
    }
#pragma unroll
    for (int j = 0; j < 4; j++) {
        atomicAdd(&lsum[cbase + j], s[j]);
        atomicAdd(&lsq[cbase + j], q[j]);
    }
    __syncthreads();
    for (int t = threadIdx.x; t < COUT; t += blockDim.x) {
        atomicAdd(&stats[t], lsum[t]);
        atomicAdd(&stats[COUT + t], lsq[t]);
    }
}

__global__ void finalize_flat(const float* __restrict__ stats,
                              const float* __restrict__ gamma,
                              const float* __restrict__ beta,
                              float invN, float* __restrict__ scaleshift) {
    int c = threadIdx.x;
    if (c < COUT) {
        float mean = stats[c] * invN;
        float var = stats[COUT + c] * invN - mean * mean;
        float sc = gamma[c] * rsqrtf(var + BN_EPS);
        scaleshift[c] = sc;
        scaleshift[COUT + c] = beta[c] - mean * sc;
    }
}

// ---------------- launch ----------------

extern "C" void kernel_launch(void* const* d_in, const int* in_sizes, int n_in,
                              void* d_out, int out_size, void* d_ws, size_t ws_size,
                              hipStream_t stream) {
    const float* feat   = (const float*)d_in[0];
    const int*   coords = (const int*)d_in[1];
    const float* W      = (const float*)d_in[2];
    const float* gamma  = (const float*)d_in[3];
    const float* beta   = (const float*)d_in[4];
    float* out = (float*)d_out;

    int N = in_sizes[0] / CIN;
    const int threads = 256;
    int blocksN = (N + threads - 1) / threads;
    long total_vec = (long)N * COUT / 4;

    size_t a256 = 255;
    size_t words_b    = (size_t)NW32 * 4;                      // 1 MB
    size_t off_bases  = (words_b + a256) & ~a256;
    size_t off_sorig  = (off_bases + (size_t)NW32 * 4 + a256) & ~a256;
    size_t off_skeys  = (off_sorig + (size_t)N * 4 + a256) & ~a256;
    size_t off_featbf = (off_skeys + (size_t)N * 4 + a256) & ~a256;
    size_t off_bcnt   = (off_featbf + (size_t)(N + 1) * 16 + a256) & ~a256;
    size_t off_bbase  = (off_bcnt + 256 * 4 + a256) & ~a256;
    size_t off_wfrag  = (off_bbase + 256 * 4 + a256) & ~a256;
    size_t off_stats  = (off_wfrag + (size_t)(7 * 2 * 64) * 16 + a256) & ~a256;
    size_t off_scsh   = off_stats + (size_t)64 * 64 * 4;
    size_t need_sorted = off_scsh + 2 * COUT * sizeof(float) + 256;

    if (ws_size >= need_sorted) {
        uint32_t* words = (uint32_t*)d_ws;
        uint32_t* bases = (uint32_t*)((char*)d_ws + off_bases);
        int*   sorig = (int*)((char*)d_ws + off_sorig);
        int*   skeys = (int*)((char*)d_ws + off_skeys);
        uint4* featb = (uint4*)((char*)d_ws + off_featbf);
        int*   bcnt  = (int*)((char*)d_ws + off_bcnt);
        int*   bbase = (int*)((char*)d_ws + off_bbase);
        uint4* wfrag = (uint4*)((char*)d_ws + off_wfrag);
        float* stats = (float*)((char*)d_ws + off_stats);
        float* scsh  = (float*)((char*)d_ws + off_scsh);

        hipMemsetAsync(words, 0, words_b, stream);
        hipMemsetAsync(featb + N, 0, 16, stream);              // zero row
        hipMemsetAsync(stats, 0, (size_t)64 * 64 * 4, stream);
        prep_wfrag<<<4, threads, 0, stream>>>(W, wfrag);
        build_bitmap32<<<blocksN, threads, 0, stream>>>(coords, N, words);
        bitmap_count32<<<NBLK32, threads, 0, stream>>>(words, bcnt);
        scan_small<<<1, threads, 0, stream>>>(bcnt, bbase, NBLK32);
        base_fill32<<<NBLK32, threads, 0, stream>>>(words, bbase, bases);
        rank_scatter32<<<blocksN, threads, 0, stream>>>(coords, feat, N, words, bases,
                                                        sorig, skeys, featb);
        int cblocks = (N + 63) / 64;
        conv_mfma<<<cblocks, threads, 0, stream>>>(featb, skeys, sorig, wfrag,
                                                   words, bases, N, out, stats);
        finalize_sliced<<<1, 64, 0, stream>>>(stats, gamma, beta, 1.0f / (float)N, scsh);
        norm_kernel<<<2048, threads, 0, stream>>>(out, total_vec, scsh);
        return;
    }

    // ---------- fallback (R2 behavior) ----------
    size_t dense_bytes = (size_t)NCELL * 4;
    bool dense = (ws_size >= dense_bytes + 512);
    size_t table_bytes;
    uint32_t bits = 22, mask = 0;
    if (dense) {
        table_bytes = dense_bytes;
    } else {
        while (bits > 20 && ((size_t)8 << bits) + 512 > ws_size) bits--;
        table_bytes = (size_t)8 << bits;
        mask = (1u << bits) - 1u;
    }
    float* stats = (float*)d_ws;
    float* scsh  = stats + 2 * COUT;

    hipMemsetAsync(d_ws, 0xFF, table_bytes, stream);
    if (dense) {
        build_dense<<<blocksN, threads, 0, stream>>>(coords, N, (int*)d_ws);
        conv_kernel<true><<<blocksN, threads, 0, stream>>>(feat, coords, W, d_ws, 0, 0, N, out);
    } else {
        build_hash<<<blocksN, threads, 0, stream>>>(coords, N, (unsigned long long*)d_ws, bits, mask);
        conv_kernel<false><<<blocksN, threads, 0, stream>>>(feat, coords, W, d_ws, bits, mask, N, out);
    }
    hipMemsetAsync(stats, 0, 2 * COUT * sizeof(float), stream);
    stats_kernel<<<1024, threads, 0, stream>>>(out, total_vec, stats);
    finalize_flat<<<1, 64, 0, stream>>>(stats, gamma, beta, 1.0f / (float)N, scsh);
    norm_kernel<<<2048, threads, 0, stream>>>(out, total_vec, scsh);
}